// Round 5
// baseline (465.411 us; speedup 1.0000x reference)
//
#include <hip/hip_runtime.h>

// Problem constants
#define BATCH 2
#define SLEN 2048
#define DMODEL 1024
#define NHEAD 16
#define HDIM 64
#define MROWS (BATCH * SLEN)   // 4096

typedef __attribute__((ext_vector_type(8))) short bf16x8;
typedef __attribute__((ext_vector_type(4))) short bf16x4;
typedef __attribute__((ext_vector_type(4))) float f32x4;
typedef __attribute__((ext_vector_type(8))) _Float16 f16x8;
typedef __attribute__((ext_vector_type(4))) _Float16 f16x4;

__device__ inline short f2bf(float x) {
    union { float f; unsigned u; } v; v.f = x;
    unsigned r = (v.u + 0x7FFFu + ((v.u >> 16) & 1u)) >> 16;
    return (short)r;
}
__device__ inline float bf2f(short h) {
    union { unsigned u; float f; } v; v.u = ((unsigned)(unsigned short)h) << 16;
    return v.f;
}
__device__ inline unsigned fbits(float x) {
    union { float f; unsigned u; } v; v.f = x; return v.u;
}
// raw hardware exp2: one v_exp_f32 (args bounded; no denormal fixup needed)
__device__ inline float hw_exp2(float x) {
    float r;
    asm("v_exp_f32 %0, %1" : "=v"(r) : "v"(x));
    return r;
}

// ---------------- prep: cast fp32 -> fp16
__global__ __launch_bounds__(256) void cast_f16(
    const float* __restrict__ in, _Float16* __restrict__ out, int n4)
{
    int i = blockIdx.x * 256 + threadIdx.x;
    if (i >= n4) return;
    float4 f = ((const float4*)in)[i];
    f16x4 h;
    h[0] = (_Float16)f.x; h[1] = (_Float16)f.y;
    h[2] = (_Float16)f.z; h[3] = (_Float16)f.w;
    ((f16x4*)out)[i] = h;
}

// ---------------- prep: transpose W[K][N] -> WT fp16 [N][K]
__global__ __launch_bounds__(256) void transpose_f16(
    const float* __restrict__ in, _Float16* __restrict__ outT, int K, int N)
{
    __shared__ float T[64][68];
    const int tid = threadIdx.x;
    const int n0 = blockIdx.x * 64, k0 = blockIdx.y * 64;
#pragma unroll
    for (int i = 0; i < 4; i++) {
        int idx = tid + i * 256;
        int r = idx >> 4, c4 = idx & 15;
        *(float4*)&T[r][c4 * 4] = *(const float4*)&in[(size_t)(k0 + r) * N + n0 + c4 * 4];
    }
    __syncthreads();
#pragma unroll
    for (int i = 0; i < 4; i++) {
        int idx = tid + i * 256;
        int n = idx >> 4, kg = idx & 15;
        f16x4 h;
#pragma unroll
        for (int j = 0; j < 4; j++)
            h[j] = (_Float16)T[kg * 4 + j][n];
        *(f16x4*)&outT[(size_t)(n0 + n) * K + k0 + kg * 4] = h;
    }
}

// ---------------- transpose V section of qkv -> vT[b][h][d][s]  (bf16)
__global__ __launch_bounds__(256) void transpose_v(
    const short* __restrict__ qkv, short* __restrict__ vT)
{
    __shared__ short T[64 * 68];   // [s][d], stride 68 shorts
    const int tid = threadIdx.x;
    const int bid = blockIdx.x;
    const int st = bid & 31, h = (bid >> 5) & 15, b = bid >> 9;
    const int s0 = st * 64;
    const short* src = qkv + (size_t)b * SLEN * (3 * DMODEL) + 2 * DMODEL + h * HDIM;

    const int srow = tid >> 3, sc8 = tid & 7;
#pragma unroll
    for (int it = 0; it < 2; it++) {
        int s = srow + it * 32;
        *(bf16x8*)&T[s * 68 + sc8 * 8] =
            *(const bf16x8*)&src[(size_t)(s0 + s) * (3 * DMODEL) + sc8 * 8];
    }
    __syncthreads();

    const int d = tid >> 2, sq = tid & 3;
    short* dst = vT + ((size_t)(b * NHEAD + h) * HDIM + d) * SLEN + s0 + sq * 16;
    bf16x8 o0, o1;
#pragma unroll
    for (int j = 0; j < 8; j++) {
        o0[j] = T[(sq * 16 + j) * 68 + d];
        o1[j] = T[(sq * 16 + 8 + j) * 68 + d];
    }
    *(bf16x8*)&dst[0] = o0;
    *(bf16x8*)&dst[8] = o1;
}

// ---------------- plain fp16 MFMA GEMM: C = A[M,K] · B[K,N] + bias
// B given TRANSPOSED [N][K] fp16. 128x128x32 tiles.
#define GSTR 40   // LDS row stride (f16 elems): 80 B, 16B-aligned, 2-way-free banks

template<int OUT_BF16>
__global__ __launch_bounds__(256) void gemm_f16(
    const _Float16* __restrict__ A, const _Float16* __restrict__ Bw,
    const float* __restrict__ bias, void* __restrict__ Cout,
    int M, int N, int K)
{
    __shared__ _Float16 As[128 * GSTR], Bs[128 * GSTR];

    const int tid  = threadIdx.x;
    const int wave = tid >> 6, lane = tid & 63;
    const int quad = lane >> 4, lr = lane & 15;
    const int wm = (wave >> 1) * 64, wn = (wave & 1) * 64;
    const int row0 = blockIdx.y * 128, col0 = blockIdx.x * 128;

    f32x4 acc[4][4];
#pragma unroll
    for (int i = 0; i < 4; i++)
#pragma unroll
        for (int j = 0; j < 4; j++) acc[i][j] = (f32x4){0.f, 0.f, 0.f, 0.f};

    const int sr = tid >> 2, sc = tid & 3;

    for (int k0 = 0; k0 < K; k0 += 32) {
        __syncthreads();
#pragma unroll
        for (int i = 0; i < 2; i++) {
            int rr = sr + i * 64;
            size_t ga = (size_t)(row0 + rr) * K + k0 + sc * 8;
            size_t gb = (size_t)(col0 + rr) * K + k0 + sc * 8;
            int ls = rr * GSTR + sc * 8;
            *(f16x8*)&As[ls] = *(const f16x8*)&A[ga];
            *(f16x8*)&Bs[ls] = *(const f16x8*)&Bw[gb];
        }
        __syncthreads();

        f16x8 af[4];
#pragma unroll
        for (int mt = 0; mt < 4; mt++)
            af[mt] = *(const f16x8*)&As[(wm + mt * 16 + lr) * GSTR + quad * 8];
#pragma unroll
        for (int nt = 0; nt < 4; nt++) {
            f16x8 b = *(const f16x8*)&Bs[(wn + nt * 16 + lr) * GSTR + quad * 8];
#pragma unroll
            for (int mt = 0; mt < 4; mt++)
                acc[mt][nt] = __builtin_amdgcn_mfma_f32_16x16x32_f16(af[mt], b, acc[mt][nt], 0, 0, 0);
        }
    }

    // epilogue: D[m = quad*4 + r][n = lr]
#pragma unroll
    for (int mt = 0; mt < 4; mt++) {
#pragma unroll
        for (int nt = 0; nt < 4; nt++) {
            int col = col0 + wn + nt * 16 + lr;
            float bv = bias[col];
#pragma unroll
            for (int r = 0; r < 4; r++) {
                int row = row0 + wm + mt * 16 + quad * 4 + r;
                float v = acc[mt][nt][r] + bv;
                if (OUT_BF16)
                    ((short*)Cout)[(size_t)row * N + col] = f2bf(v);
                else
                    ((float*)Cout)[(size_t)row * N + col] = v;
            }
        }
    }
}

// ---------------- fused attention v12: split KEYS across waves.
// v9/v11 were LDS-read-bound: all 4 waves read the SAME full K/V tiles
// (80 KB LDS traffic per block per kt, ~10 MB/CU ~= the whole runtime).
// Now wave w owns key sub-tile ct=w and holds ALL 64 q-rows in registers:
// per-wave LDS reads drop 4x (2 KB K-slice + 2 KB V-slice per kt). O and
// the softmax denominator become key-partial per wave -> one cross-wave
// LDS reduction in the epilogue (amortized over 32 K-tiles).
// Staging/ASTR=76/double-buffer/barrier identical to v11 (passed, 0 conflicts).
#define ASTR 76   // LDS row stride (shorts): measured 0 conflicts
#define NT   (SLEN / 64)
#define RSTR 20   // epilogue float row stride (80 B, 16B-aligned)
#define QK_SCALE_LOG2E 0.1803368801111244f   // 0.125 * log2(e)

__global__ __launch_bounds__(256) void attn_mfma(
    const short* __restrict__ qkv, const short* __restrict__ vT,
    _Float16* __restrict__ attn)
{
    // LDS pool: main loop uses [2][64*ASTR] K + [2][64*ASTR] V (38912 B);
    // epilogue reuses it as float [4][64][RSTR] (20480 B).
    __shared__ __align__(16) char smem[2 * 64 * ASTR * 2 * 2];
    short* KsBuf = (short*)smem;                           // [2][64*ASTR]
    short* VtBuf = (short*)(smem + 2 * 64 * ASTR * 2);     // [2][64*ASTR]

    const int tid  = threadIdx.x;
    const int lane = tid & 63;
    const int wave = tid >> 6;           // = this wave's key sub-tile (ct)
    const int quad = lane >> 4;
    const int lr   = lane & 15;

    const int bid = blockIdx.x;
    const int qt = bid & 31;             // 32 q-tiles of 64
    const int h  = (bid >> 5) & 15;
    const int b  = bid >> 9;
    const int q0 = qt * 64;

    const short* qbase = qkv + (size_t)b * SLEN * (3 * DMODEL) + h * HDIM;
    const short* kbase = qbase + DMODEL;
    const short* vtbase = vT + (size_t)(b * NHEAD + h) * HDIM * SLEN;

    // ALL 4 q-subtiles as 16x16x32 B-frags, pre-scaled:
    // qf[qs][ds2][j] = Q[q0 + qs*16 + lr][ds2*32 + quad*8 + j] * scale
    bf16x8 qf[4][2];
#pragma unroll
    for (int qs = 0; qs < 4; qs++)
#pragma unroll
        for (int ds2 = 0; ds2 < 2; ds2++) {
            bf16x8 q = *(const bf16x8*)&qbase[(size_t)(q0 + qs * 16 + lr) * (3 * DMODEL) + ds2 * 32 + quad * 8];
#pragma unroll
            for (int j = 0; j < 8; j++)
                q[j] = f2bf(bf2f(q[j]) * QK_SCALE_LOG2E);
            qf[qs][ds2] = q;
        }

    // ones A-fragment for the row-sum MFMA (x16 shape)
    bf16x4 ones;
#pragma unroll
    for (int j = 0; j < 4; j++) ones[j] = (short)0x3F80;

    f32x4 oacc[4][4];   // [qs][dt]: O^T partial for THIS wave's keys
#pragma unroll
    for (int qs = 0; qs < 4; qs++)
#pragma unroll
        for (int t = 0; t < 4; t++) oacc[qs][t] = (f32x4){0.f, 0.f, 0.f, 0.f};
    f32x4 sacc[4];      // [qs]: rowsum partial for THIS wave's keys
#pragma unroll
    for (int qs = 0; qs < 4; qs++) sacc[qs] = (f32x4){0.f, 0.f, 0.f, 0.f};

    const int srow = tid >> 3, sc8 = tid & 7;

    // pointer-bumped staging addresses (identical to v11)
    const short* kp0 = kbase + (size_t)srow * (3 * DMODEL) + sc8 * 8;
    const short* kp1 = kp0 + 32 * (3 * DMODEL);
    const short* vp0 = vtbase + (size_t)srow * SLEN + sc8 * 8;
    const short* vp1 = vp0 + 32 * SLEN;

    bf16x8 kpre[2], vpre[2];
    kpre[0] = *(const bf16x8*)kp0; kpre[1] = *(const bf16x8*)kp1;
    vpre[0] = *(const bf16x8*)vp0; vpre[1] = *(const bf16x8*)vp1;
    kp0 += 64 * (3 * DMODEL); kp1 += 64 * (3 * DMODEL);
    vp0 += 64; vp1 += 64;

    // this wave's fixed LDS read offsets
    const int krow = (wave * 16 + lr) * ASTR;   // K rows wave*16+lr
    const int vcol = wave * 16 + quad * 4;      // V^T cols wave*16+quad*4

    for (int kt = 0; kt < NT; kt++) {
        const int cur = kt & 1;
        short* ks = KsBuf + cur * 64 * ASTR;
        short* vt = VtBuf + cur * 64 * ASTR;

        // write tile kt (in regs) to LDS buffer `cur`
        *(bf16x8*)&ks[srow * ASTR + sc8 * 8] = kpre[0];
        *(bf16x8*)&ks[(srow + 32) * ASTR + sc8 * 8] = kpre[1];
        *(bf16x8*)&vt[srow * ASTR + sc8 * 8] = vpre[0];
        *(bf16x8*)&vt[(srow + 32) * ASTR + sc8 * 8] = vpre[1];

        // issue global loads for tile kt+1
        if (kt + 1 < NT) {
            kpre[0] = *(const bf16x8*)kp0; kpre[1] = *(const bf16x8*)kp1;
            vpre[0] = *(const bf16x8*)vp0; vpre[1] = *(const bf16x8*)vp1;
            kp0 += 64 * (3 * DMODEL); kp1 += 64 * (3 * DMODEL);
            vp0 += 64; vp1 += 64;
        }

        __syncthreads();   // buffer `cur` complete; reads of 1-cur done pre-barrier

        // this wave's K slice (16 rows x 64 cols) -- 4x b64 + shuffle (8B-aligned rows)
        bf16x4 k0a = *(const bf16x4*)&ks[krow + quad * 8];
        bf16x4 k0b = *(const bf16x4*)&ks[krow + quad * 8 + 4];
        bf16x4 k1a = *(const bf16x4*)&ks[krow + 32 + quad * 8];
        bf16x4 k1b = *(const bf16x4*)&ks[krow + 32 + quad * 8 + 4];
        bf16x8 kf0 = __builtin_shufflevector(k0a, k0b, 0, 1, 2, 3, 4, 5, 6, 7);
        bf16x8 kf1 = __builtin_shufflevector(k1a, k1b, 0, 1, 2, 3, 4, 5, 6, 7);

        // this wave's V slice (64 d x 16 k)
        bf16x4 vf[4];
#pragma unroll
        for (int dt = 0; dt < 4; dt++)
            vf[dt] = *(const bf16x4*)&vt[(dt * 16 + lr) * ASTR + vcol];

        // 4 independent chains: S^T = K·Q^T (x32), exp2, O^T += V^T·P^T (x16)
#pragma unroll
        for (int qs = 0; qs < 4; qs++) {
            f32x4 st = {0.f, 0.f, 0.f, 0.f};
            st = __builtin_amdgcn_mfma_f32_16x16x32_bf16(kf0, qf[qs][0], st, 0, 0, 0);
            st = __builtin_amdgcn_mfma_f32_16x16x32_bf16(kf1, qf[qs][1], st, 0, 0, 0);

            float p0[4];
#pragma unroll
            for (int r = 0; r < 4; r++) p0[r] = hw_exp2(st[r]);
            union { uint2 u; bf16x4 v; } pk0;
            pk0.u.x = __builtin_amdgcn_perm(fbits(p0[1]), fbits(p0[0]), 0x07060302u);
            pk0.u.y = __builtin_amdgcn_perm(fbits(p0[3]), fbits(p0[2]), 0x07060302u);
            bf16x4 pf0 = pk0.v;

            sacc[qs] = __builtin_amdgcn_mfma_f32_16x16x16bf16_1k(ones, pf0, sacc[qs], 0, 0, 0);
#pragma unroll
            for (int dt = 0; dt < 4; dt++)
                oacc[qs][dt] = __builtin_amdgcn_mfma_f32_16x16x16bf16_1k(vf[dt], pf0, oacc[qs][dt], 0, 0, 0);
        }
    }

    // ---- epilogue: cross-wave (cross-key) reduction, then write O
    __syncthreads();                       // all main-loop LDS reads done
    float* Lf = (float*)smem;              // [4 waves][64 lanes][RSTR]
    float* myrow = Lf + (wave * 64 + lane) * RSTR;

#pragma unroll 1
    for (int qs = 0; qs < 4; qs++) {
#pragma unroll
        for (int dt = 0; dt < 4; dt++)
            *(f32x4*)&myrow[dt * 4] = oacc[qs][dt];
        myrow[16] = sacc[qs][0];
        __syncthreads();
        if (wave == qs) {
            f32x4 o[4];
#pragma unroll
            for (int dt = 0; dt < 4; dt++) o[dt] = (f32x4){0.f, 0.f, 0.f, 0.f};
            float s = 0.f;
#pragma unroll
            for (int w = 0; w < 4; w++) {
                const float* r2 = Lf + (w * 64 + lane) * RSTR;
#pragma unroll
                for (int dt = 0; dt < 4; dt++)
                    o[dt] += *(const f32x4*)&r2[dt * 4];
                s += r2[16];
            }
            const float inv = 1.0f / s;
            const int row = b * SLEN + q0 + qs * 16 + lr;
#pragma unroll
            for (int dt = 0; dt < 4; dt++) {
                f16x4 h4;
#pragma unroll
                for (int r = 0; r < 4; r++)
                    h4[r] = (_Float16)(o[dt][r] * inv);
                int col = h * HDIM + dt * 16 + quad * 4;
                *(f16x4*)&attn[(size_t)row * DMODEL + col] = h4;
            }
        }
        __syncthreads();                   // reads done before next qs overwrites
    }
}

extern "C" void kernel_launch(void* const* d_in, const int* in_sizes, int n_in,
                              void* d_out, int out_size, void* d_ws, size_t ws_size,
                              hipStream_t stream) {
    (void)in_sizes; (void)n_in; (void)out_size; (void)ws_size;
    const float* x     = (const float*)d_in[0];
    const float* Wqkv  = (const float*)d_in[1];
    const float* bqkv  = (const float*)d_in[2];
    const float* Wproj = (const float*)d_in[3];
    const float* bproj = (const float*)d_in[4];
    float* out = (float*)d_out;

    // workspace layout (2-byte units), peak ~58.6 MB
    short* qkv = (short*)d_ws;                               // 4096*3072 bf16
    _Float16* xf = (_Float16*)(qkv + (size_t)MROWS * 3 * DMODEL);  // 4096*1024 f16
    _Float16* wq = xf + (size_t)MROWS * DMODEL;              // 3072*1024 f16 (W_qkv^T)
    _Float16* wp = wq + (size_t)3 * DMODEL * DMODEL;         // 1024*1024 f16 (W_proj^T)
    short* vT = (short*)(wp + (size_t)DMODEL * DMODEL);      // 4096*1024 bf16
    _Float16* attnb = (_Float16*)(vT + (size_t)MROWS * DMODEL); // 4096*1024 f16

    // prep: cast x to fp16; transpose weights to fp16
    cast_f16<<<dim3(MROWS * DMODEL / 4 / 256), 256, 0, stream>>>(x, xf, MROWS * DMODEL / 4);
    transpose_f16<<<dim3(3 * DMODEL / 64, DMODEL / 64), 256, 0, stream>>>(Wqkv, wq, DMODEL, 3 * DMODEL);
    transpose_f16<<<dim3(DMODEL / 64, DMODEL / 64), 256, 0, stream>>>(Wproj, wp, DMODEL, DMODEL);

    // 1) qkv(bf16) = x @ W_qkv + b_qkv   (plain fp16 MFMA)
    gemm_f16<1><<<dim3(3 * DMODEL / 128, MROWS / 128), 256, 0, stream>>>(
        xf, wq, bqkv, (void*)qkv, MROWS, 3 * DMODEL, DMODEL);

    // 1b) transpose V section -> vT[b][h][d][s]
    transpose_v<<<dim3(BATCH * NHEAD * (SLEN / 64)), 256, 0, stream>>>(qkv, vT);

    // 2) fused attention: bf16 qkv + vT -> attn (fp16); 64 q-rows/block,
    //    keys split across the 4 waves
    attn_mfma<<<dim3(BATCH * NHEAD * (SLEN / 64)), 256, 0, stream>>>(qkv, vT, attnb);

    // 3) out(fp32) = attn @ W_proj + b_proj   (plain fp16 MFMA)
    gemm_f16<0><<<dim3(DMODEL / 128, MROWS / 128), 256, 0, stream>>>(
        attnb, wp, bproj, (void*)out, MROWS, DMODEL, DMODEL);
}

// Round 6
// 239.059 us; speedup vs baseline: 1.9468x; 1.9468x over previous
//
#include <hip/hip_runtime.h>

// Problem constants
#define BATCH 2
#define SLEN 2048
#define DMODEL 1024
#define NHEAD 16
#define HDIM 64
#define MROWS (BATCH * SLEN)   // 4096

typedef __attribute__((ext_vector_type(8))) short bf16x8;
typedef __attribute__((ext_vector_type(4))) short bf16x4;
typedef __attribute__((ext_vector_type(4))) float f32x4;
typedef __attribute__((ext_vector_type(8))) _Float16 f16x8;
typedef __attribute__((ext_vector_type(4))) _Float16 f16x4;

__device__ inline short f2bf(float x) {
    union { float f; unsigned u; } v; v.f = x;
    unsigned r = (v.u + 0x7FFFu + ((v.u >> 16) & 1u)) >> 16;
    return (short)r;
}
__device__ inline float bf2f(short h) {
    union { unsigned u; float f; } v; v.u = ((unsigned)(unsigned short)h) << 16;
    return v.f;
}
__device__ inline unsigned fbits(float x) {
    union { float f; unsigned u; } v; v.f = x; return v.u;
}
// raw hardware exp2: one v_exp_f32 (args bounded; no denormal fixup needed)
__device__ inline float hw_exp2(float x) {
    float r;
    asm("v_exp_f32 %0, %1" : "=v"(r) : "v"(x));
    return r;
}

// ---------------- prep: cast fp32 -> fp16
__global__ __launch_bounds__(256) void cast_f16(
    const float* __restrict__ in, _Float16* __restrict__ out, int n4)
{
    int i = blockIdx.x * 256 + threadIdx.x;
    if (i >= n4) return;
    float4 f = ((const float4*)in)[i];
    f16x4 h;
    h[0] = (_Float16)f.x; h[1] = (_Float16)f.y;
    h[2] = (_Float16)f.z; h[3] = (_Float16)f.w;
    ((f16x4*)out)[i] = h;
}

// ---------------- prep: transpose W[K][N] -> WT fp16 [N][K]
__global__ __launch_bounds__(256) void transpose_f16(
    const float* __restrict__ in, _Float16* __restrict__ outT, int K, int N)
{
    __shared__ float T[64][68];
    const int tid = threadIdx.x;
    const int n0 = blockIdx.x * 64, k0 = blockIdx.y * 64;
#pragma unroll
    for (int i = 0; i < 4; i++) {
        int idx = tid + i * 256;
        int r = idx >> 4, c4 = idx & 15;
        *(float4*)&T[r][c4 * 4] = *(const float4*)&in[(size_t)(k0 + r) * N + n0 + c4 * 4];
    }
    __syncthreads();
#pragma unroll
    for (int i = 0; i < 4; i++) {
        int idx = tid + i * 256;
        int n = idx >> 4, kg = idx & 15;
        f16x4 h;
#pragma unroll
        for (int j = 0; j < 4; j++)
            h[j] = (_Float16)T[kg * 4 + j][n];
        *(f16x4*)&outT[(size_t)(n0 + n) * K + k0 + kg * 4] = h;
    }
}

// ---------------- transpose V section of qkv -> vT[b][h][d][s]  (bf16)
__global__ __launch_bounds__(256) void transpose_v(
    const short* __restrict__ qkv, short* __restrict__ vT)
{
    __shared__ short T[64 * 68];   // [s][d], stride 68 shorts
    const int tid = threadIdx.x;
    const int bid = blockIdx.x;
    const int st = bid & 31, h = (bid >> 5) & 15, b = bid >> 9;
    const int s0 = st * 64;
    const short* src = qkv + (size_t)b * SLEN * (3 * DMODEL) + 2 * DMODEL + h * HDIM;

    const int srow = tid >> 3, sc8 = tid & 7;
#pragma unroll
    for (int it = 0; it < 2; it++) {
        int s = srow + it * 32;
        *(bf16x8*)&T[s * 68 + sc8 * 8] =
            *(const bf16x8*)&src[(size_t)(s0 + s) * (3 * DMODEL) + sc8 * 8];
    }
    __syncthreads();

    const int d = tid >> 2, sq = tid & 3;
    short* dst = vT + ((size_t)(b * NHEAD + h) * HDIM + d) * SLEN + s0 + sq * 16;
    bf16x8 o0, o1;
#pragma unroll
    for (int j = 0; j < 8; j++) {
        o0[j] = T[(sq * 16 + j) * 68 + d];
        o1[j] = T[(sq * 16 + 8 + j) * 68 + d];
    }
    *(bf16x8*)&dst[0] = o0;
    *(bf16x8*)&dst[8] = o1;
}

// ---------------- plain fp16 MFMA GEMM: C = A[M,K] · B[K,N] + bias
// B given TRANSPOSED [N][K] fp16. 128x128x32 tiles.
#define GSTR 40   // LDS row stride (f16 elems): 80 B, 16B-aligned, 2-way-free banks

template<int OUT_BF16>
__global__ __launch_bounds__(256) void gemm_f16(
    const _Float16* __restrict__ A, const _Float16* __restrict__ Bw,
    const float* __restrict__ bias, void* __restrict__ Cout,
    int M, int N, int K)
{
    __shared__ _Float16 As[128 * GSTR], Bs[128 * GSTR];

    const int tid  = threadIdx.x;
    const int wave = tid >> 6, lane = tid & 63;
    const int quad = lane >> 4, lr = lane & 15;
    const int wm = (wave >> 1) * 64, wn = (wave & 1) * 64;
    const int row0 = blockIdx.y * 128, col0 = blockIdx.x * 128;

    f32x4 acc[4][4];
#pragma unroll
    for (int i = 0; i < 4; i++)
#pragma unroll
        for (int j = 0; j < 4; j++) acc[i][j] = (f32x4){0.f, 0.f, 0.f, 0.f};

    const int sr = tid >> 2, sc = tid & 3;

    for (int k0 = 0; k0 < K; k0 += 32) {
        __syncthreads();
#pragma unroll
        for (int i = 0; i < 2; i++) {
            int rr = sr + i * 64;
            size_t ga = (size_t)(row0 + rr) * K + k0 + sc * 8;
            size_t gb = (size_t)(col0 + rr) * K + k0 + sc * 8;
            int ls = rr * GSTR + sc * 8;
            *(f16x8*)&As[ls] = *(const f16x8*)&A[ga];
            *(f16x8*)&Bs[ls] = *(const f16x8*)&Bw[gb];
        }
        __syncthreads();

        f16x8 af[4];
#pragma unroll
        for (int mt = 0; mt < 4; mt++)
            af[mt] = *(const f16x8*)&As[(wm + mt * 16 + lr) * GSTR + quad * 8];
#pragma unroll
        for (int nt = 0; nt < 4; nt++) {
            f16x8 b = *(const f16x8*)&Bs[(wn + nt * 16 + lr) * GSTR + quad * 8];
#pragma unroll
            for (int mt = 0; mt < 4; mt++)
                acc[mt][nt] = __builtin_amdgcn_mfma_f32_16x16x32_f16(af[mt], b, acc[mt][nt], 0, 0, 0);
        }
    }

    // epilogue: D[m = quad*4 + r][n = lr]
#pragma unroll
    for (int mt = 0; mt < 4; mt++) {
#pragma unroll
        for (int nt = 0; nt < 4; nt++) {
            int col = col0 + wn + nt * 16 + lr;
            float bv = bias[col];
#pragma unroll
            for (int r = 0; r < 4; r++) {
                int row = row0 + wm + mt * 16 + quad * 4 + r;
                float v = acc[mt][nt][r] + bv;
                if (OUT_BF16)
                    ((short*)Cout)[(size_t)row * N + col] = f2bf(v);
                else
                    ((float*)Cout)[(size_t)row * N + col] = v;
            }
        }
    }
}

// ---------------- fused attention v13: v12 (keys split across waves) with
// the scratch-demotion bug fixed. v12's epilogue used `#pragma unroll 1` +
// runtime qs indexing of oacc/sacc -> compiler demoted ALL accumulators to
// scratch (WRITE_SIZE 8MB -> 1.78GB, kernel became scratch-BW-bound at
// 6.2 TB/s; rule #20). Fix: fully unroll the epilogue so every accumulator
// index is compile-time. Main loop unchanged (passed, 0 main-loop conflicts).
#define ASTR 76   // LDS row stride (shorts): measured 0 conflicts
#define NT   (SLEN / 64)
#define RSTR 20   // epilogue float row stride (80 B, 16B-aligned)
#define QK_SCALE_LOG2E 0.1803368801111244f   // 0.125 * log2(e)

__global__ __launch_bounds__(256) void attn_mfma(
    const short* __restrict__ qkv, const short* __restrict__ vT,
    _Float16* __restrict__ attn)
{
    // LDS pool: main loop uses [2][64*ASTR] K + [2][64*ASTR] V (38912 B);
    // epilogue reuses it as float [4][64][RSTR] (20480 B).
    __shared__ __align__(16) char smem[2 * 64 * ASTR * 2 * 2];
    short* KsBuf = (short*)smem;                           // [2][64*ASTR]
    short* VtBuf = (short*)(smem + 2 * 64 * ASTR * 2);     // [2][64*ASTR]

    const int tid  = threadIdx.x;
    const int lane = tid & 63;
    const int wave = tid >> 6;           // = this wave's key sub-tile (ct)
    const int quad = lane >> 4;
    const int lr   = lane & 15;

    const int bid = blockIdx.x;
    const int qt = bid & 31;             // 32 q-tiles of 64
    const int h  = (bid >> 5) & 15;
    const int b  = bid >> 9;
    const int q0 = qt * 64;

    const short* qbase = qkv + (size_t)b * SLEN * (3 * DMODEL) + h * HDIM;
    const short* kbase = qbase + DMODEL;
    const short* vtbase = vT + (size_t)(b * NHEAD + h) * HDIM * SLEN;

    // ALL 4 q-subtiles as 16x16x32 B-frags, pre-scaled:
    // qf[qs][ds2][j] = Q[q0 + qs*16 + lr][ds2*32 + quad*8 + j] * scale
    bf16x8 qf[4][2];
#pragma unroll
    for (int qs = 0; qs < 4; qs++)
#pragma unroll
        for (int ds2 = 0; ds2 < 2; ds2++) {
            bf16x8 q = *(const bf16x8*)&qbase[(size_t)(q0 + qs * 16 + lr) * (3 * DMODEL) + ds2 * 32 + quad * 8];
#pragma unroll
            for (int j = 0; j < 8; j++)
                q[j] = f2bf(bf2f(q[j]) * QK_SCALE_LOG2E);
            qf[qs][ds2] = q;
        }

    // ones A-fragment for the row-sum MFMA (x16 shape)
    bf16x4 ones;
#pragma unroll
    for (int j = 0; j < 4; j++) ones[j] = (short)0x3F80;

    f32x4 oacc[4][4];   // [qs][dt]: O^T partial for THIS wave's keys
#pragma unroll
    for (int qs = 0; qs < 4; qs++)
#pragma unroll
        for (int t = 0; t < 4; t++) oacc[qs][t] = (f32x4){0.f, 0.f, 0.f, 0.f};
    f32x4 sacc[4];      // [qs]: rowsum partial for THIS wave's keys
#pragma unroll
    for (int qs = 0; qs < 4; qs++) sacc[qs] = (f32x4){0.f, 0.f, 0.f, 0.f};

    const int srow = tid >> 3, sc8 = tid & 7;

    // pointer-bumped staging addresses
    const short* kp0 = kbase + (size_t)srow * (3 * DMODEL) + sc8 * 8;
    const short* kp1 = kp0 + 32 * (3 * DMODEL);
    const short* vp0 = vtbase + (size_t)srow * SLEN + sc8 * 8;
    const short* vp1 = vp0 + 32 * SLEN;

    bf16x8 kpre[2], vpre[2];
    kpre[0] = *(const bf16x8*)kp0; kpre[1] = *(const bf16x8*)kp1;
    vpre[0] = *(const bf16x8*)vp0; vpre[1] = *(const bf16x8*)vp1;
    kp0 += 64 * (3 * DMODEL); kp1 += 64 * (3 * DMODEL);
    vp0 += 64; vp1 += 64;

    // this wave's fixed LDS read offsets
    const int krow = (wave * 16 + lr) * ASTR;   // K rows wave*16+lr
    const int vcol = wave * 16 + quad * 4;      // V^T cols wave*16+quad*4

    for (int kt = 0; kt < NT; kt++) {
        const int cur = kt & 1;
        short* ks = KsBuf + cur * 64 * ASTR;
        short* vt = VtBuf + cur * 64 * ASTR;

        // write tile kt (in regs) to LDS buffer `cur`
        *(bf16x8*)&ks[srow * ASTR + sc8 * 8] = kpre[0];
        *(bf16x8*)&ks[(srow + 32) * ASTR + sc8 * 8] = kpre[1];
        *(bf16x8*)&vt[srow * ASTR + sc8 * 8] = vpre[0];
        *(bf16x8*)&vt[(srow + 32) * ASTR + sc8 * 8] = vpre[1];

        // issue global loads for tile kt+1
        if (kt + 1 < NT) {
            kpre[0] = *(const bf16x8*)kp0; kpre[1] = *(const bf16x8*)kp1;
            vpre[0] = *(const bf16x8*)vp0; vpre[1] = *(const bf16x8*)vp1;
            kp0 += 64 * (3 * DMODEL); kp1 += 64 * (3 * DMODEL);
            vp0 += 64; vp1 += 64;
        }

        __syncthreads();   // buffer `cur` complete; reads of 1-cur done pre-barrier

        // this wave's K slice (16 rows x 64 cols) -- 4x b64 + shuffle (8B-aligned rows)
        bf16x4 k0a = *(const bf16x4*)&ks[krow + quad * 8];
        bf16x4 k0b = *(const bf16x4*)&ks[krow + quad * 8 + 4];
        bf16x4 k1a = *(const bf16x4*)&ks[krow + 32 + quad * 8];
        bf16x4 k1b = *(const bf16x4*)&ks[krow + 32 + quad * 8 + 4];
        bf16x8 kf0 = __builtin_shufflevector(k0a, k0b, 0, 1, 2, 3, 4, 5, 6, 7);
        bf16x8 kf1 = __builtin_shufflevector(k1a, k1b, 0, 1, 2, 3, 4, 5, 6, 7);

        // this wave's V slice (64 d x 16 k)
        bf16x4 vf[4];
#pragma unroll
        for (int dt = 0; dt < 4; dt++)
            vf[dt] = *(const bf16x4*)&vt[(dt * 16 + lr) * ASTR + vcol];

        // 4 independent chains: S^T = K·Q^T (x32), exp2, O^T += V^T·P^T (x16)
#pragma unroll
        for (int qs = 0; qs < 4; qs++) {
            f32x4 st = {0.f, 0.f, 0.f, 0.f};
            st = __builtin_amdgcn_mfma_f32_16x16x32_bf16(kf0, qf[qs][0], st, 0, 0, 0);
            st = __builtin_amdgcn_mfma_f32_16x16x32_bf16(kf1, qf[qs][1], st, 0, 0, 0);

            float p0[4];
#pragma unroll
            for (int r = 0; r < 4; r++) p0[r] = hw_exp2(st[r]);
            union { uint2 u; bf16x4 v; } pk0;
            pk0.u.x = __builtin_amdgcn_perm(fbits(p0[1]), fbits(p0[0]), 0x07060302u);
            pk0.u.y = __builtin_amdgcn_perm(fbits(p0[3]), fbits(p0[2]), 0x07060302u);
            bf16x4 pf0 = pk0.v;

            sacc[qs] = __builtin_amdgcn_mfma_f32_16x16x16bf16_1k(ones, pf0, sacc[qs], 0, 0, 0);
#pragma unroll
            for (int dt = 0; dt < 4; dt++)
                oacc[qs][dt] = __builtin_amdgcn_mfma_f32_16x16x16bf16_1k(vf[dt], pf0, oacc[qs][dt], 0, 0, 0);
        }
    }

    // ---- epilogue: cross-wave (cross-key) reduction, then write O.
    // FULLY UNROLLED: every oacc/sacc index must be compile-time (rule #20 —
    // runtime indexing demotes the accumulators to scratch for the WHOLE kernel).
    __syncthreads();                       // all main-loop LDS reads done
    float* Lf = (float*)smem;              // [4 waves][64 lanes][RSTR]
    float* myrow = Lf + (wave * 64 + lane) * RSTR;

#pragma unroll
    for (int qs = 0; qs < 4; qs++) {
#pragma unroll
        for (int dt = 0; dt < 4; dt++)
            *(f32x4*)&myrow[dt * 4] = oacc[qs][dt];
        myrow[16] = sacc[qs][0];
        __syncthreads();
        if (wave == qs) {
            f32x4 o[4];
#pragma unroll
            for (int dt = 0; dt < 4; dt++) o[dt] = (f32x4){0.f, 0.f, 0.f, 0.f};
            float s = 0.f;
#pragma unroll
            for (int w = 0; w < 4; w++) {
                const float* r2 = Lf + (w * 64 + lane) * RSTR;
#pragma unroll
                for (int dt = 0; dt < 4; dt++)
                    o[dt] += *(const f32x4*)&r2[dt * 4];
                s += r2[16];
            }
            const float inv = 1.0f / s;
            const int row = b * SLEN + q0 + qs * 16 + lr;
#pragma unroll
            for (int dt = 0; dt < 4; dt++) {
                f16x4 h4;
#pragma unroll
                for (int r = 0; r < 4; r++)
                    h4[r] = (_Float16)(o[dt][r] * inv);
                int col = h * HDIM + dt * 16 + quad * 4;
                *(f16x4*)&attn[(size_t)row * DMODEL + col] = h4;
            }
        }
        __syncthreads();                   // reads done before next qs overwrites
    }
}

extern "C" void kernel_launch(void* const* d_in, const int* in_sizes, int n_in,
                              void* d_out, int out_size, void* d_ws, size_t ws_size,
                              hipStream_t stream) {
    (void)in_sizes; (void)n_in; (void)out_size; (void)ws_size;
    const float* x     = (const float*)d_in[0];
    const float* Wqkv  = (const float*)d_in[1];
    const float* bqkv  = (const float*)d_in[2];
    const float* Wproj = (const float*)d_in[3];
    const float* bproj = (const float*)d_in[4];
    float* out = (float*)d_out;

    // workspace layout (2-byte units), peak ~58.6 MB
    short* qkv = (short*)d_ws;                               // 4096*3072 bf16
    _Float16* xf = (_Float16*)(qkv + (size_t)MROWS * 3 * DMODEL);  // 4096*1024 f16
    _Float16* wq = xf + (size_t)MROWS * DMODEL;              // 3072*1024 f16 (W_qkv^T)
    _Float16* wp = wq + (size_t)3 * DMODEL * DMODEL;         // 1024*1024 f16 (W_proj^T)
    short* vT = (short*)(wp + (size_t)DMODEL * DMODEL);      // 4096*1024 bf16
    _Float16* attnb = (_Float16*)(vT + (size_t)MROWS * DMODEL); // 4096*1024 f16

    // prep: cast x to fp16; transpose weights to fp16
    cast_f16<<<dim3(MROWS * DMODEL / 4 / 256), 256, 0, stream>>>(x, xf, MROWS * DMODEL / 4);
    transpose_f16<<<dim3(3 * DMODEL / 64, DMODEL / 64), 256, 0, stream>>>(Wqkv, wq, DMODEL, 3 * DMODEL);
    transpose_f16<<<dim3(DMODEL / 64, DMODEL / 64), 256, 0, stream>>>(Wproj, wp, DMODEL, DMODEL);

    // 1) qkv(bf16) = x @ W_qkv + b_qkv   (plain fp16 MFMA)
    gemm_f16<1><<<dim3(3 * DMODEL / 128, MROWS / 128), 256, 0, stream>>>(
        xf, wq, bqkv, (void*)qkv, MROWS, 3 * DMODEL, DMODEL);

    // 1b) transpose V section -> vT[b][h][d][s]
    transpose_v<<<dim3(BATCH * NHEAD * (SLEN / 64)), 256, 0, stream>>>(qkv, vT);

    // 2) fused attention: bf16 qkv + vT -> attn (fp16); 64 q-rows/block,
    //    keys split across the 4 waves
    attn_mfma<<<dim3(BATCH * NHEAD * (SLEN / 64)), 256, 0, stream>>>(qkv, vT, attnb);

    // 3) out(fp32) = attn @ W_proj + b_proj   (plain fp16 MFMA)
    gemm_f16<0><<<dim3(DMODEL / 128, MROWS / 128), 256, 0, stream>>>(
        attnb, wp, bproj, (void*)out, MROWS, DMODEL, DMODEL);
}

// Round 7
// 209.375 us; speedup vs baseline: 2.2229x; 1.1418x over previous
//
#include <hip/hip_runtime.h>

// Problem constants
#define BATCH 2
#define SLEN 2048
#define DMODEL 1024
#define NHEAD 16
#define HDIM 64
#define MROWS (BATCH * SLEN)   // 4096

typedef __attribute__((ext_vector_type(8))) short bf16x8;
typedef __attribute__((ext_vector_type(4))) short bf16x4;
typedef __attribute__((ext_vector_type(4))) float f32x4;
typedef __attribute__((ext_vector_type(8))) _Float16 f16x8;
typedef __attribute__((ext_vector_type(4))) _Float16 f16x4;

__device__ inline short f2bf(float x) {
    union { float f; unsigned u; } v; v.f = x;
    unsigned r = (v.u + 0x7FFFu + ((v.u >> 16) & 1u)) >> 16;
    return (short)r;
}
__device__ inline float bf2f(short h) {
    union { unsigned u; float f; } v; v.u = ((unsigned)(unsigned short)h) << 16;
    return v.f;
}
__device__ inline unsigned fbits(float x) {
    union { float f; unsigned u; } v; v.f = x; return v.u;
}
// raw hardware exp2: one v_exp_f32 (args bounded; no denormal fixup needed)
__device__ inline float hw_exp2(float x) {
    float r;
    asm("v_exp_f32 %0, %1" : "=v"(r) : "v"(x));
    return r;
}

// ---------------- prep: cast fp32 -> fp16
__global__ __launch_bounds__(256) void cast_f16(
    const float* __restrict__ in, _Float16* __restrict__ out, int n4)
{
    int i = blockIdx.x * 256 + threadIdx.x;
    if (i >= n4) return;
    float4 f = ((const float4*)in)[i];
    f16x4 h;
    h[0] = (_Float16)f.x; h[1] = (_Float16)f.y;
    h[2] = (_Float16)f.z; h[3] = (_Float16)f.w;
    ((f16x4*)out)[i] = h;
}

// ---------------- prep: transpose W[K][N] -> WT fp16 [N][K]
__global__ __launch_bounds__(256) void transpose_f16(
    const float* __restrict__ in, _Float16* __restrict__ outT, int K, int N)
{
    __shared__ float T[64][68];
    const int tid = threadIdx.x;
    const int n0 = blockIdx.x * 64, k0 = blockIdx.y * 64;
#pragma unroll
    for (int i = 0; i < 4; i++) {
        int idx = tid + i * 256;
        int r = idx >> 4, c4 = idx & 15;
        *(float4*)&T[r][c4 * 4] = *(const float4*)&in[(size_t)(k0 + r) * N + n0 + c4 * 4];
    }
    __syncthreads();
#pragma unroll
    for (int i = 0; i < 4; i++) {
        int idx = tid + i * 256;
        int n = idx >> 4, kg = idx & 15;
        f16x4 h;
#pragma unroll
        for (int j = 0; j < 4; j++)
            h[j] = (_Float16)T[kg * 4 + j][n];
        *(f16x4*)&outT[(size_t)(n0 + n) * K + k0 + kg * 4] = h;
    }
}

// ---------------- transpose V section of qkv -> vT[b][h][d][s]  (bf16)
__global__ __launch_bounds__(256) void transpose_v(
    const short* __restrict__ qkv, short* __restrict__ vT)
{
    __shared__ short T[64 * 68];   // [s][d], stride 68 shorts
    const int tid = threadIdx.x;
    const int bid = blockIdx.x;
    const int st = bid & 31, h = (bid >> 5) & 15, b = bid >> 9;
    const int s0 = st * 64;
    const short* src = qkv + (size_t)b * SLEN * (3 * DMODEL) + 2 * DMODEL + h * HDIM;

    const int srow = tid >> 3, sc8 = tid & 7;
#pragma unroll
    for (int it = 0; it < 2; it++) {
        int s = srow + it * 32;
        *(bf16x8*)&T[s * 68 + sc8 * 8] =
            *(const bf16x8*)&src[(size_t)(s0 + s) * (3 * DMODEL) + sc8 * 8];
    }
    __syncthreads();

    const int d = tid >> 2, sq = tid & 3;
    short* dst = vT + ((size_t)(b * NHEAD + h) * HDIM + d) * SLEN + s0 + sq * 16;
    bf16x8 o0, o1;
#pragma unroll
    for (int j = 0; j < 8; j++) {
        o0[j] = T[(sq * 16 + j) * 68 + d];
        o1[j] = T[(sq * 16 + 8 + j) * 68 + d];
    }
    *(bf16x8*)&dst[0] = o0;
    *(bf16x8*)&dst[8] = o1;
}

// ---------------- plain fp16 MFMA GEMM: C = A[M,K] · B[K,N] + bias
// B given TRANSPOSED [N][K] fp16. 128x128x32 tiles.
// v14: 2-phase register prefetch — next K-tile is loaded into regs while the
// current tile computes (previously the global loads were issued and consumed
// inside the same phase: latency fully exposed). Same barrier count.
#define GSTR 40   // LDS row stride (f16 elems): 80 B, 2-way-free banks (measured)

template<int OUT_BF16>
__global__ __launch_bounds__(256) void gemm_f16(
    const _Float16* __restrict__ A, const _Float16* __restrict__ Bw,
    const float* __restrict__ bias, void* __restrict__ Cout,
    int M, int N, int K)
{
    __shared__ _Float16 As[128 * GSTR], Bs[128 * GSTR];

    const int tid  = threadIdx.x;
    const int wave = tid >> 6, lane = tid & 63;
    const int quad = lane >> 4, lr = lane & 15;
    const int wm = (wave >> 1) * 64, wn = (wave & 1) * 64;
    const int row0 = blockIdx.y * 128, col0 = blockIdx.x * 128;

    f32x4 acc[4][4];
#pragma unroll
    for (int i = 0; i < 4; i++)
#pragma unroll
        for (int j = 0; j < 4; j++) acc[i][j] = (f32x4){0.f, 0.f, 0.f, 0.f};

    const int sr = tid >> 2, sc = tid & 3;

    // staging pointers: rows sr and sr+64, K-offset sc*8
    const _Float16* ap0 = A  + (size_t)(row0 + sr) * K + sc * 8;
    const _Float16* ap1 = ap0 + (size_t)64 * K;
    const _Float16* bp0 = Bw + (size_t)(col0 + sr) * K + sc * 8;
    const _Float16* bp1 = bp0 + (size_t)64 * K;

    f16x8 apre[2], bpre[2];
    apre[0] = *(const f16x8*)ap0; apre[1] = *(const f16x8*)ap1;
    bpre[0] = *(const f16x8*)bp0; bpre[1] = *(const f16x8*)bp1;
    ap0 += 32; ap1 += 32; bp0 += 32; bp1 += 32;

    const int ls = sr * GSTR + sc * 8;

    for (int k0 = 0; k0 < K; k0 += 32) {
        // write prefetched tile to LDS (prev compute's reads done: trailing barrier)
        *(f16x8*)&As[ls] = apre[0];
        *(f16x8*)&As[ls + 64 * GSTR] = apre[1];
        *(f16x8*)&Bs[ls] = bpre[0];
        *(f16x8*)&Bs[ls + 64 * GSTR] = bpre[1];

        // issue global loads for tile k0+32 (hidden under this tile's compute)
        if (k0 + 32 < K) {
            apre[0] = *(const f16x8*)ap0; apre[1] = *(const f16x8*)ap1;
            bpre[0] = *(const f16x8*)bp0; bpre[1] = *(const f16x8*)bp1;
            ap0 += 32; ap1 += 32; bp0 += 32; bp1 += 32;
        }

        __syncthreads();

        f16x8 af[4];
#pragma unroll
        for (int mt = 0; mt < 4; mt++)
            af[mt] = *(const f16x8*)&As[(wm + mt * 16 + lr) * GSTR + quad * 8];
#pragma unroll
        for (int nt = 0; nt < 4; nt++) {
            f16x8 b = *(const f16x8*)&Bs[(wn + nt * 16 + lr) * GSTR + quad * 8];
#pragma unroll
            for (int mt = 0; mt < 4; mt++)
                acc[mt][nt] = __builtin_amdgcn_mfma_f32_16x16x32_f16(af[mt], b, acc[mt][nt], 0, 0, 0);
        }

        __syncthreads();   // reads done; next iter may overwrite LDS
    }

    // epilogue: D[m = quad*4 + r][n = lr]
#pragma unroll
    for (int mt = 0; mt < 4; mt++) {
#pragma unroll
        for (int nt = 0; nt < 4; nt++) {
            int col = col0 + wn + nt * 16 + lr;
            float bv = bias[col];
#pragma unroll
            for (int r = 0; r < 4; r++) {
                int row = row0 + wm + mt * 16 + quad * 4 + r;
                float v = acc[mt][nt][r] + bv;
                if (OUT_BF16)
                    ((short*)Cout)[(size_t)row * N + col] = f2bf(v);
                else
                    ((float*)Cout)[(size_t)row * N + col] = v;
            }
        }
    }
}

// ---------------- fused attention: v9 (best measured: 71.0 µs). 64 q-rows
// per block (4 blocks/CU), QK^T via 16x16x32 bf16 MFMA, x16 PV. ASTR=72's
// 12.6M bank-conflict cycles measured ~3% cost (overlapped) — cheaper than
// every attempted "fix" (v11 b64-loads: 83 µs; v13 key-split: 94.5 µs).
#define ASTR 72   // LDS row stride (shorts): 144 B, 16B-aligned rows
#define NT   (SLEN / 64)
#define QK_SCALE_LOG2E 0.1803368801111244f   // 0.125 * log2(e)

__global__ __launch_bounds__(256) void attn_mfma(
    const short* __restrict__ qkv, const short* __restrict__ vT,
    _Float16* __restrict__ attn)
{
    __shared__ short Ks[2][64 * ASTR];   // K tile, row-major [k][d]
    __shared__ short Vt[2][64 * ASTR];   // V^T tile [d][k]

    const int tid  = threadIdx.x;
    const int lane = tid & 63;
    const int wave = tid >> 6;
    const int quad = lane >> 4;
    const int lr   = lane & 15;
    const int wq0  = wave * 16;          // wave owns 16 q-rows

    const int bid = blockIdx.x;
    const int qt = bid & 31;             // 32 q-tiles of 64
    const int h  = (bid >> 5) & 15;
    const int b  = bid >> 9;
    const int q0 = qt * 64;

    const short* qbase = qkv + (size_t)b * SLEN * (3 * DMODEL) + h * HDIM;
    const short* kbase = qbase + DMODEL;
    const short* vtbase = vT + (size_t)(b * NHEAD + h) * HDIM * SLEN;

    // Q as 16x16x32 B-frags, pre-scaled: qf[ds2][j] = Q[q=lr][d = ds2*32 + quad*8 + j]
    bf16x8 qf[2];
#pragma unroll
    for (int ds2 = 0; ds2 < 2; ds2++) {
        bf16x8 q = *(const bf16x8*)&qbase[(size_t)(q0 + wq0 + lr) * (3 * DMODEL) + ds2 * 32 + quad * 8];
#pragma unroll
        for (int j = 0; j < 8; j++)
            q[j] = f2bf(bf2f(q[j]) * QK_SCALE_LOG2E);
        qf[ds2] = q;
    }

    // ones A-fragment for the row-sum MFMA (x16 shape)
    bf16x4 ones;
#pragma unroll
    for (int j = 0; j < 4; j++) ones[j] = (short)0x3F80;

    f32x4 oacc[4];   // O^T tiles: D[d = dt*16+quad*4+r][q = lr]
#pragma unroll
    for (int t = 0; t < 4; t++) oacc[t] = (f32x4){0.f, 0.f, 0.f, 0.f};
    f32x4 sacc = {0.f, 0.f, 0.f, 0.f};

    const int srow = tid >> 3, sc8 = tid & 7;

    // pointer-bumped staging addresses
    const short* kp0 = kbase + (size_t)srow * (3 * DMODEL) + sc8 * 8;
    const short* kp1 = kp0 + 32 * (3 * DMODEL);
    const short* vp0 = vtbase + (size_t)srow * SLEN + sc8 * 8;
    const short* vp1 = vp0 + 32 * SLEN;

    bf16x8 kpre[2], vpre[2];
    kpre[0] = *(const bf16x8*)kp0; kpre[1] = *(const bf16x8*)kp1;
    vpre[0] = *(const bf16x8*)vp0; vpre[1] = *(const bf16x8*)vp1;
    kp0 += 64 * (3 * DMODEL); kp1 += 64 * (3 * DMODEL);
    vp0 += 64; vp1 += 64;

    for (int kt = 0; kt < NT; kt++) {
        const int cur = kt & 1;
        short* ks = Ks[cur];
        short* vt = Vt[cur];

        // write tile kt (in regs) to LDS buffer `cur`
        *(bf16x8*)&ks[srow * ASTR + sc8 * 8] = kpre[0];
        *(bf16x8*)&ks[(srow + 32) * ASTR + sc8 * 8] = kpre[1];
        *(bf16x8*)&vt[srow * ASTR + sc8 * 8] = vpre[0];
        *(bf16x8*)&vt[(srow + 32) * ASTR + sc8 * 8] = vpre[1];

        // issue global loads for tile kt+1
        if (kt + 1 < NT) {
            kpre[0] = *(const bf16x8*)kp0; kpre[1] = *(const bf16x8*)kp1;
            vpre[0] = *(const bf16x8*)vp0; vpre[1] = *(const bf16x8*)vp1;
            kp0 += 64 * (3 * DMODEL); kp1 += 64 * (3 * DMODEL);
            vp0 += 64; vp1 += 64;
        }

        __syncthreads();   // buffer `cur` complete; reads of 1-cur done pre-barrier

        // per 16-key tile: S^T = K·Q^T (x32 MFMA), exp2, O^T += V^T·P^T (x16)
#pragma unroll
        for (int ct = 0; ct < 4; ct++) {
            bf16x8 kf0 = *(const bf16x8*)&ks[(ct * 16 + lr) * ASTR + quad * 8];
            bf16x8 kf1 = *(const bf16x8*)&ks[(ct * 16 + lr) * ASTR + 32 + quad * 8];

            f32x4 st = {0.f, 0.f, 0.f, 0.f};
            st = __builtin_amdgcn_mfma_f32_16x16x32_bf16(kf0, qf[0], st, 0, 0, 0);
            st = __builtin_amdgcn_mfma_f32_16x16x32_bf16(kf1, qf[1], st, 0, 0, 0);

            float p0[4];
#pragma unroll
            for (int r = 0; r < 4; r++) p0[r] = hw_exp2(st[r]);
            union { uint2 u; bf16x4 v; } pk0;
            pk0.u.x = __builtin_amdgcn_perm(fbits(p0[1]), fbits(p0[0]), 0x07060302u);
            pk0.u.y = __builtin_amdgcn_perm(fbits(p0[3]), fbits(p0[2]), 0x07060302u);
            bf16x4 pf0 = pk0.v;

            sacc = __builtin_amdgcn_mfma_f32_16x16x16bf16_1k(ones, pf0, sacc, 0, 0, 0);
#pragma unroll
            for (int dt = 0; dt < 4; dt++) {
                bf16x4 vf = *(const bf16x4*)&vt[(dt * 16 + lr) * ASTR + ct * 16 + quad * 4];
                oacc[dt] = __builtin_amdgcn_mfma_f32_16x16x16bf16_1k(vf, pf0, oacc[dt], 0, 0, 0);
            }
        }
    }

    // write O as plain fp16 for the proj GEMM
    {
        const float inv = 1.0f / sacc[0];
        const int row = b * SLEN + q0 + wq0 + lr;
#pragma unroll
        for (int dt = 0; dt < 4; dt++) {
            f16x4 h4;
#pragma unroll
            for (int r = 0; r < 4; r++)
                h4[r] = (_Float16)(oacc[dt][r] * inv);
            int col = h * HDIM + dt * 16 + quad * 4;
            *(f16x4*)&attn[(size_t)row * DMODEL + col] = h4;
        }
    }
}

extern "C" void kernel_launch(void* const* d_in, const int* in_sizes, int n_in,
                              void* d_out, int out_size, void* d_ws, size_t ws_size,
                              hipStream_t stream) {
    (void)in_sizes; (void)n_in; (void)out_size; (void)ws_size;
    const float* x     = (const float*)d_in[0];
    const float* Wqkv  = (const float*)d_in[1];
    const float* bqkv  = (const float*)d_in[2];
    const float* Wproj = (const float*)d_in[3];
    const float* bproj = (const float*)d_in[4];
    float* out = (float*)d_out;

    // workspace layout (2-byte units), peak ~58.6 MB
    short* qkv = (short*)d_ws;                               // 4096*3072 bf16
    _Float16* xf = (_Float16*)(qkv + (size_t)MROWS * 3 * DMODEL);  // 4096*1024 f16
    _Float16* wq = xf + (size_t)MROWS * DMODEL;              // 3072*1024 f16 (W_qkv^T)
    _Float16* wp = wq + (size_t)3 * DMODEL * DMODEL;         // 1024*1024 f16 (W_proj^T)
    short* vT = (short*)(wp + (size_t)DMODEL * DMODEL);      // 4096*1024 bf16
    _Float16* attnb = (_Float16*)(vT + (size_t)MROWS * DMODEL); // 4096*1024 f16

    // prep: cast x to fp16; transpose weights to fp16
    cast_f16<<<dim3(MROWS * DMODEL / 4 / 256), 256, 0, stream>>>(x, xf, MROWS * DMODEL / 4);
    transpose_f16<<<dim3(3 * DMODEL / 64, DMODEL / 64), 256, 0, stream>>>(Wqkv, wq, DMODEL, 3 * DMODEL);
    transpose_f16<<<dim3(DMODEL / 64, DMODEL / 64), 256, 0, stream>>>(Wproj, wp, DMODEL, DMODEL);

    // 1) qkv(bf16) = x @ W_qkv + b_qkv   (plain fp16 MFMA, 2-phase pipelined)
    gemm_f16<1><<<dim3(3 * DMODEL / 128, MROWS / 128), 256, 0, stream>>>(
        xf, wq, bqkv, (void*)qkv, MROWS, 3 * DMODEL, DMODEL);

    // 1b) transpose V section -> vT[b][h][d][s]
    transpose_v<<<dim3(BATCH * NHEAD * (SLEN / 64)), 256, 0, stream>>>(qkv, vT);

    // 2) fused attention: bf16 qkv + vT -> attn (fp16); 64 q-rows/block
    attn_mfma<<<dim3(BATCH * NHEAD * (SLEN / 64)), 256, 0, stream>>>(qkv, vT, attnb);

    // 3) out(fp32) = attn @ W_proj + b_proj   (plain fp16 MFMA, 2-phase pipelined)
    gemm_f16<0><<<dim3(DMODEL / 128, MROWS / 128), 256, 0, stream>>>(
        attnb, wp, bproj, (void*)out, MROWS, DMODEL, DMODEL);
}

// Round 9
// 206.172 us; speedup vs baseline: 2.2574x; 1.0155x over previous
//
#include <hip/hip_runtime.h>

// Problem constants
#define BATCH 2
#define SLEN 2048
#define DMODEL 1024
#define NHEAD 16
#define HDIM 64
#define MROWS (BATCH * SLEN)   // 4096

typedef __attribute__((ext_vector_type(8))) short bf16x8;
typedef __attribute__((ext_vector_type(4))) short bf16x4;
typedef __attribute__((ext_vector_type(4))) float f32x4;
typedef __attribute__((ext_vector_type(8))) _Float16 f16x8;
typedef __attribute__((ext_vector_type(4))) _Float16 f16x4;

__device__ inline short f2bf(float x) {
    union { float f; unsigned u; } v; v.f = x;
    unsigned r = (v.u + 0x7FFFu + ((v.u >> 16) & 1u)) >> 16;
    return (short)r;
}
__device__ inline float bf2f(short h) {
    union { unsigned u; float f; } v; v.u = ((unsigned)(unsigned short)h) << 16;
    return v.f;
}
__device__ inline unsigned fbits(float x) {
    union { float f; unsigned u; } v; v.f = x; return v.u;
}
// raw hardware exp2: one v_exp_f32 (args bounded; no denormal fixup needed)
__device__ inline float hw_exp2(float x) {
    float r;
    asm("v_exp_f32 %0, %1" : "=v"(r) : "v"(x));
    return r;
}

// ---------------- prep: cast fp32 -> fp16
__global__ __launch_bounds__(256) void cast_f16(
    const float* __restrict__ in, _Float16* __restrict__ out, int n4)
{
    int i = blockIdx.x * 256 + threadIdx.x;
    if (i >= n4) return;
    float4 f = ((const float4*)in)[i];
    f16x4 h;
    h[0] = (_Float16)f.x; h[1] = (_Float16)f.y;
    h[2] = (_Float16)f.z; h[3] = (_Float16)f.w;
    ((f16x4*)out)[i] = h;
}

// ---------------- prep: transpose W[K][N] -> WT fp16 [N][K]
__global__ __launch_bounds__(256) void transpose_f16(
    const float* __restrict__ in, _Float16* __restrict__ outT, int K, int N)
{
    __shared__ float T[64][68];
    const int tid = threadIdx.x;
    const int n0 = blockIdx.x * 64, k0 = blockIdx.y * 64;
#pragma unroll
    for (int i = 0; i < 4; i++) {
        int idx = tid + i * 256;
        int r = idx >> 4, c4 = idx & 15;
        *(float4*)&T[r][c4 * 4] = *(const float4*)&in[(size_t)(k0 + r) * N + n0 + c4 * 4];
    }
    __syncthreads();
#pragma unroll
    for (int i = 0; i < 4; i++) {
        int idx = tid + i * 256;
        int n = idx >> 4, kg = idx & 15;
        f16x4 h;
#pragma unroll
        for (int j = 0; j < 4; j++)
            h[j] = (_Float16)T[kg * 4 + j][n];
        *(f16x4*)&outT[(size_t)(n0 + n) * K + k0 + kg * 4] = h;
    }
}

// ---------------- transpose V section of qkv -> vT[b][h][d][s]  (bf16)
__global__ __launch_bounds__(256) void transpose_v(
    const short* __restrict__ qkv, short* __restrict__ vT)
{
    __shared__ short T[64 * 68];   // [s][d], stride 68 shorts
    const int tid = threadIdx.x;
    const int bid = blockIdx.x;
    const int st = bid & 31, h = (bid >> 5) & 15, b = bid >> 9;
    const int s0 = st * 64;
    const short* src = qkv + (size_t)b * SLEN * (3 * DMODEL) + 2 * DMODEL + h * HDIM;

    const int srow = tid >> 3, sc8 = tid & 7;
#pragma unroll
    for (int it = 0; it < 2; it++) {
        int s = srow + it * 32;
        *(bf16x8*)&T[s * 68 + sc8 * 8] =
            *(const bf16x8*)&src[(size_t)(s0 + s) * (3 * DMODEL) + sc8 * 8];
    }
    __syncthreads();

    const int d = tid >> 2, sq = tid & 3;
    short* dst = vT + ((size_t)(b * NHEAD + h) * HDIM + d) * SLEN + s0 + sq * 16;
    bf16x8 o0, o1;
#pragma unroll
    for (int j = 0; j < 8; j++) {
        o0[j] = T[(sq * 16 + j) * 68 + d];
        o1[j] = T[(sq * 16 + 8 + j) * 68 + d];
    }
    *(bf16x8*)&dst[0] = o0;
    *(bf16x8*)&dst[8] = o1;
}

// ---------------- plain fp16 MFMA GEMM: C = A[M,K] · B[K,N] + bias
// B given TRANSPOSED [N][K] fp16. 128x128x32 tiles.
// v14 (kept: measured ~17 µs total gain): 2-phase register prefetch — next
// K-tile loads into regs while the current tile computes.
#define GSTR 40   // LDS row stride (f16 elems): 80 B, 2-way-free banks (measured)

template<int OUT_BF16>
__global__ __launch_bounds__(256) void gemm_f16(
    const _Float16* __restrict__ A, const _Float16* __restrict__ Bw,
    const float* __restrict__ bias, void* __restrict__ Cout,
    int M, int N, int K)
{
    __shared__ _Float16 As[128 * GSTR], Bs[128 * GSTR];

    const int tid  = threadIdx.x;
    const int wave = tid >> 6, lane = tid & 63;
    const int quad = lane >> 4, lr = lane & 15;
    const int wm = (wave >> 1) * 64, wn = (wave & 1) * 64;
    const int row0 = blockIdx.y * 128, col0 = blockIdx.x * 128;

    f32x4 acc[4][4];
#pragma unroll
    for (int i = 0; i < 4; i++)
#pragma unroll
        for (int j = 0; j < 4; j++) acc[i][j] = (f32x4){0.f, 0.f, 0.f, 0.f};

    const int sr = tid >> 2, sc = tid & 3;

    // staging pointers: rows sr and sr+64, K-offset sc*8
    const _Float16* ap0 = A  + (size_t)(row0 + sr) * K + sc * 8;
    const _Float16* ap1 = ap0 + (size_t)64 * K;
    const _Float16* bp0 = Bw + (size_t)(col0 + sr) * K + sc * 8;
    const _Float16* bp1 = bp0 + (size_t)64 * K;

    f16x8 apre[2], bpre[2];
    apre[0] = *(const f16x8*)ap0; apre[1] = *(const f16x8*)ap1;
    bpre[0] = *(const f16x8*)bp0; bpre[1] = *(const f16x8*)bp1;
    ap0 += 32; ap1 += 32; bp0 += 32; bp1 += 32;

    const int ls = sr * GSTR + sc * 8;

    for (int k0 = 0; k0 < K; k0 += 32) {
        // write prefetched tile to LDS (prev compute's reads done: trailing barrier)
        *(f16x8*)&As[ls] = apre[0];
        *(f16x8*)&As[ls + 64 * GSTR] = apre[1];
        *(f16x8*)&Bs[ls] = bpre[0];
        *(f16x8*)&Bs[ls + 64 * GSTR] = bpre[1];

        // issue global loads for tile k0+32 (hidden under this tile's compute)
        if (k0 + 32 < K) {
            apre[0] = *(const f16x8*)ap0; apre[1] = *(const f16x8*)ap1;
            bpre[0] = *(const f16x8*)bp0; bpre[1] = *(const f16x8*)bp1;
            ap0 += 32; ap1 += 32; bp0 += 32; bp1 += 32;
        }

        __syncthreads();

        f16x8 af[4];
#pragma unroll
        for (int mt = 0; mt < 4; mt++)
            af[mt] = *(const f16x8*)&As[(wm + mt * 16 + lr) * GSTR + quad * 8];
#pragma unroll
        for (int nt = 0; nt < 4; nt++) {
            f16x8 b = *(const f16x8*)&Bs[(wn + nt * 16 + lr) * GSTR + quad * 8];
#pragma unroll
            for (int mt = 0; mt < 4; mt++)
                acc[mt][nt] = __builtin_amdgcn_mfma_f32_16x16x32_f16(af[mt], b, acc[mt][nt], 0, 0, 0);
        }

        __syncthreads();   // reads done; next iter may overwrite LDS
    }

    // epilogue: D[m = quad*4 + r][n = lr]
#pragma unroll
    for (int mt = 0; mt < 4; mt++) {
#pragma unroll
        for (int nt = 0; nt < 4; nt++) {
            int col = col0 + wn + nt * 16 + lr;
            float bv = bias[col];
#pragma unroll
            for (int r = 0; r < 4; r++) {
                int row = row0 + wm + mt * 16 + quad * 4 + r;
                float v = acc[mt][nt][r] + bv;
                if (OUT_BF16)
                    ((short*)Cout)[(size_t)row * N + col] = f2bf(v);
                else
                    ((float*)Cout)[(size_t)row * N + col] = v;
            }
        }
    }
}

// ---------------- fused attention v16: identical to v15 (q/ct split per wave,
// pair-reduce epilogue) EXCEPT plain __launch_bounds__(256). Hypothesis under
// test: the forced min-occupancy (256,4) VGPR cap (spill codegen) is what broke
// BOTH failing kernels (v10, v15) — every passing kernel used plain (256);
// v13 passed with this exact epilogue pattern. One-token A/B.
#define ASTR 72   // LDS row stride (shorts): 144 B, 16B-aligned rows
#define NT   (SLEN / 64)
#define RSTR 20   // epilogue float row stride (80 B, 16B-aligned)
#define QK_SCALE_LOG2E 0.1803368801111244f   // 0.125 * log2(e)

__global__ __launch_bounds__(256) void attn_mfma(
    const short* __restrict__ qkv, const short* __restrict__ vT,
    _Float16* __restrict__ attn)
{
    // single pool: main loop = Ks[2][64*ASTR] + Vt[2][64*ASTR] shorts (36864 B);
    // epilogue reuses it as float [4][64][RSTR] (20480 B).
    __shared__ __align__(16) char smem[2 * 64 * ASTR * 2 * 2];
    short* KsBuf = (short*)smem;
    short* VtBuf = KsBuf + 2 * 64 * ASTR;

    const int tid  = threadIdx.x;
    const int lane = tid & 63;
    const int wave = tid >> 6;
    const int quad = lane >> 4;
    const int lr   = lane & 15;
    const int qhalf  = wave >> 1;        // which 32-q half this wave owns
    const int cthalf = wave & 1;         // which ct pair this wave owns

    const int bid = blockIdx.x;
    const int qt = bid & 31;             // 32 q-tiles of 64
    const int h  = (bid >> 5) & 15;
    const int b  = bid >> 9;
    const int q0 = qt * 64;

    const short* qbase = qkv + (size_t)b * SLEN * (3 * DMODEL) + h * HDIM;
    const short* kbase = qbase + DMODEL;
    const short* vtbase = vT + (size_t)(b * NHEAD + h) * HDIM * SLEN;

    // 2 q-subtiles as 16x16x32 B-frags, pre-scaled:
    // qf[qs][ds2][j] = Q[q0 + qhalf*32 + qs*16 + lr][ds2*32 + quad*8 + j]
    bf16x8 qf[2][2];
#pragma unroll
    for (int qs = 0; qs < 2; qs++)
#pragma unroll
        for (int ds2 = 0; ds2 < 2; ds2++) {
            bf16x8 q = *(const bf16x8*)&qbase[(size_t)(q0 + qhalf * 32 + qs * 16 + lr) * (3 * DMODEL) + ds2 * 32 + quad * 8];
#pragma unroll
            for (int j = 0; j < 8; j++)
                q[j] = f2bf(bf2f(q[j]) * QK_SCALE_LOG2E);
            qf[qs][ds2] = q;
        }

    // ones A-fragment for the row-sum MFMA (x16 shape)
    bf16x4 ones;
#pragma unroll
    for (int j = 0; j < 4; j++) ones[j] = (short)0x3F80;

    f32x4 oacc[2][4];   // [qs][dt]: O^T partial over this wave's keys
#pragma unroll
    for (int qs = 0; qs < 2; qs++)
#pragma unroll
        for (int t = 0; t < 4; t++) oacc[qs][t] = (f32x4){0.f, 0.f, 0.f, 0.f};
    f32x4 sacc[2] = {{0.f, 0.f, 0.f, 0.f}, {0.f, 0.f, 0.f, 0.f}};

    const int srow = tid >> 3, sc8 = tid & 7;

    // pointer-bumped staging addresses (all 4 waves stage the full tile — unchanged)
    const short* kp0 = kbase + (size_t)srow * (3 * DMODEL) + sc8 * 8;
    const short* kp1 = kp0 + 32 * (3 * DMODEL);
    const short* vp0 = vtbase + (size_t)srow * SLEN + sc8 * 8;
    const short* vp1 = vp0 + 32 * SLEN;

    bf16x8 kpre[2], vpre[2];
    kpre[0] = *(const bf16x8*)kp0; kpre[1] = *(const bf16x8*)kp1;
    vpre[0] = *(const bf16x8*)vp0; vpre[1] = *(const bf16x8*)vp1;
    kp0 += 64 * (3 * DMODEL); kp1 += 64 * (3 * DMODEL);
    vp0 += 64; vp1 += 64;

    for (int kt = 0; kt < NT; kt++) {
        const int cur = kt & 1;
        short* ks = KsBuf + cur * 64 * ASTR;
        short* vt = VtBuf + cur * 64 * ASTR;

        // write tile kt (in regs) to LDS buffer `cur`
        *(bf16x8*)&ks[srow * ASTR + sc8 * 8] = kpre[0];
        *(bf16x8*)&ks[(srow + 32) * ASTR + sc8 * 8] = kpre[1];
        *(bf16x8*)&vt[srow * ASTR + sc8 * 8] = vpre[0];
        *(bf16x8*)&vt[(srow + 32) * ASTR + sc8 * 8] = vpre[1];

        // issue global loads for tile kt+1
        if (kt + 1 < NT) {
            kpre[0] = *(const bf16x8*)kp0; kpre[1] = *(const bf16x8*)kp1;
            vpre[0] = *(const bf16x8*)vp0; vpre[1] = *(const bf16x8*)vp1;
            kp0 += 64 * (3 * DMODEL); kp1 += 64 * (3 * DMODEL);
            vp0 += 64; vp1 += 64;
        }

        __syncthreads();   // buffer `cur` complete; reads of 1-cur done pre-barrier

        // this wave's 2 key sub-tiles x 2 q-subtiles (4 chains/kt, same as v9)
#pragma unroll
        for (int ct2 = 0; ct2 < 2; ct2++) {
            const int ct = cthalf * 2 + ct2;
            bf16x8 kf0 = *(const bf16x8*)&ks[(ct * 16 + lr) * ASTR + quad * 8];
            bf16x8 kf1 = *(const bf16x8*)&ks[(ct * 16 + lr) * ASTR + 32 + quad * 8];
            bf16x4 vf0 = *(const bf16x4*)&vt[(0 * 16 + lr) * ASTR + ct * 16 + quad * 4];
            bf16x4 vf1 = *(const bf16x4*)&vt[(1 * 16 + lr) * ASTR + ct * 16 + quad * 4];
            bf16x4 vf2 = *(const bf16x4*)&vt[(2 * 16 + lr) * ASTR + ct * 16 + quad * 4];
            bf16x4 vf3 = *(const bf16x4*)&vt[(3 * 16 + lr) * ASTR + ct * 16 + quad * 4];

#pragma unroll
            for (int qs = 0; qs < 2; qs++) {
                f32x4 st = {0.f, 0.f, 0.f, 0.f};
                st = __builtin_amdgcn_mfma_f32_16x16x32_bf16(kf0, qf[qs][0], st, 0, 0, 0);
                st = __builtin_amdgcn_mfma_f32_16x16x32_bf16(kf1, qf[qs][1], st, 0, 0, 0);

                float p0[4];
#pragma unroll
                for (int r = 0; r < 4; r++) p0[r] = hw_exp2(st[r]);
                union { uint2 u; bf16x4 v; } pk0;
                pk0.u.x = __builtin_amdgcn_perm(fbits(p0[1]), fbits(p0[0]), 0x07060302u);
                pk0.u.y = __builtin_amdgcn_perm(fbits(p0[3]), fbits(p0[2]), 0x07060302u);
                bf16x4 pf0 = pk0.v;

                sacc[qs] = __builtin_amdgcn_mfma_f32_16x16x16bf16_1k(ones, pf0, sacc[qs], 0, 0, 0);
                oacc[qs][0] = __builtin_amdgcn_mfma_f32_16x16x16bf16_1k(vf0, pf0, oacc[qs][0], 0, 0, 0);
                oacc[qs][1] = __builtin_amdgcn_mfma_f32_16x16x16bf16_1k(vf1, pf0, oacc[qs][1], 0, 0, 0);
                oacc[qs][2] = __builtin_amdgcn_mfma_f32_16x16x16bf16_1k(vf2, pf0, oacc[qs][2], 0, 0, 0);
                oacc[qs][3] = __builtin_amdgcn_mfma_f32_16x16x16bf16_1k(vf3, pf0, oacc[qs][3], 0, 0, 0);
            }
        }
    }

    // ---- epilogue: pair (wave, wave^1) shares qhalf; reduce over cthalf.
    // Round qs: waves with cthalf!=qs stage; waves with cthalf==qs read the
    // partner row, add to their registers, and write O. All indices static.
    __syncthreads();                       // all main-loop LDS reads done
    float* Lf = (float*)smem;              // [4 waves][64 lanes][RSTR]
    float* myrow = Lf + (wave * 64 + lane) * RSTR;

    // round 0 stage (cthalf==1)
    if (cthalf == 1) {
        *(f32x4*)&myrow[0]  = oacc[0][0];
        *(f32x4*)&myrow[4]  = oacc[0][1];
        *(f32x4*)&myrow[8]  = oacc[0][2];
        *(f32x4*)&myrow[12] = oacc[0][3];
        myrow[16] = sacc[0][0];
    }
    __syncthreads();
    if (cthalf == 0) {
        // finalize qs=0
        const float* pr = Lf + ((wave ^ 1) * 64 + lane) * RSTR;
        f32x4 o0 = oacc[0][0] + *(const f32x4*)&pr[0];
        f32x4 o1 = oacc[0][1] + *(const f32x4*)&pr[4];
        f32x4 o2 = oacc[0][2] + *(const f32x4*)&pr[8];
        f32x4 o3 = oacc[0][3] + *(const f32x4*)&pr[12];
        const float inv = 1.0f / (sacc[0][0] + pr[16]);
        const int row = b * SLEN + q0 + qhalf * 32 + lr;
        f16x4 h4;
#pragma unroll
        for (int r = 0; r < 4; r++) h4[r] = (_Float16)(o0[r] * inv);
        *(f16x4*)&attn[(size_t)row * DMODEL + h * HDIM + 0 * 16 + quad * 4] = h4;
#pragma unroll
        for (int r = 0; r < 4; r++) h4[r] = (_Float16)(o1[r] * inv);
        *(f16x4*)&attn[(size_t)row * DMODEL + h * HDIM + 1 * 16 + quad * 4] = h4;
#pragma unroll
        for (int r = 0; r < 4; r++) h4[r] = (_Float16)(o2[r] * inv);
        *(f16x4*)&attn[(size_t)row * DMODEL + h * HDIM + 2 * 16 + quad * 4] = h4;
#pragma unroll
        for (int r = 0; r < 4; r++) h4[r] = (_Float16)(o3[r] * inv);
        *(f16x4*)&attn[(size_t)row * DMODEL + h * HDIM + 3 * 16 + quad * 4] = h4;
        // round 1 stage (cthalf==0)
        *(f32x4*)&myrow[0]  = oacc[1][0];
        *(f32x4*)&myrow[4]  = oacc[1][1];
        *(f32x4*)&myrow[8]  = oacc[1][2];
        *(f32x4*)&myrow[12] = oacc[1][3];
        myrow[16] = sacc[1][0];
    }
    __syncthreads();
    if (cthalf == 1) {
        // finalize qs=1
        const float* pr = Lf + ((wave ^ 1) * 64 + lane) * RSTR;
        f32x4 o0 = oacc[1][0] + *(const f32x4*)&pr[0];
        f32x4 o1 = oacc[1][1] + *(const f32x4*)&pr[4];
        f32x4 o2 = oacc[1][2] + *(const f32x4*)&pr[8];
        f32x4 o3 = oacc[1][3] + *(const f32x4*)&pr[12];
        const float inv = 1.0f / (sacc[1][0] + pr[16]);
        const int row = b * SLEN + q0 + qhalf * 32 + 16 + lr;
        f16x4 h4;
#pragma unroll
        for (int r = 0; r < 4; r++) h4[r] = (_Float16)(o0[r] * inv);
        *(f16x4*)&attn[(size_t)row * DMODEL + h * HDIM + 0 * 16 + quad * 4] = h4;
#pragma unroll
        for (int r = 0; r < 4; r++) h4[r] = (_Float16)(o1[r] * inv);
        *(f16x4*)&attn[(size_t)row * DMODEL + h * HDIM + 1 * 16 + quad * 4] = h4;
#pragma unroll
        for (int r = 0; r < 4; r++) h4[r] = (_Float16)(o2[r] * inv);
        *(f16x4*)&attn[(size_t)row * DMODEL + h * HDIM + 2 * 16 + quad * 4] = h4;
#pragma unroll
        for (int r = 0; r < 4; r++) h4[r] = (_Float16)(o3[r] * inv);
        *(f16x4*)&attn[(size_t)row * DMODEL + h * HDIM + 3 * 16 + quad * 4] = h4;
    }
}

extern "C" void kernel_launch(void* const* d_in, const int* in_sizes, int n_in,
                              void* d_out, int out_size, void* d_ws, size_t ws_size,
                              hipStream_t stream) {
    (void)in_sizes; (void)n_in; (void)out_size; (void)ws_size;
    const float* x     = (const float*)d_in[0];
    const float* Wqkv  = (const float*)d_in[1];
    const float* bqkv  = (const float*)d_in[2];
    const float* Wproj = (const float*)d_in[3];
    const float* bproj = (const float*)d_in[4];
    float* out = (float*)d_out;

    // workspace layout (2-byte units), peak ~58.6 MB
    short* qkv = (short*)d_ws;                               // 4096*3072 bf16
    _Float16* xf = (_Float16*)(qkv + (size_t)MROWS * 3 * DMODEL);  // 4096*1024 f16
    _Float16* wq = xf + (size_t)MROWS * DMODEL;              // 3072*1024 f16 (W_qkv^T)
    _Float16* wp = wq + (size_t)3 * DMODEL * DMODEL;         // 1024*1024 f16 (W_proj^T)
    short* vT = (short*)(wp + (size_t)DMODEL * DMODEL);      // 4096*1024 bf16
    _Float16* attnb = (_Float16*)(vT + (size_t)MROWS * DMODEL); // 4096*1024 f16

    // prep: cast x to fp16; transpose weights to fp16
    cast_f16<<<dim3(MROWS * DMODEL / 4 / 256), 256, 0, stream>>>(x, xf, MROWS * DMODEL / 4);
    transpose_f16<<<dim3(3 * DMODEL / 64, DMODEL / 64), 256, 0, stream>>>(Wqkv, wq, DMODEL, 3 * DMODEL);
    transpose_f16<<<dim3(DMODEL / 64, DMODEL / 64), 256, 0, stream>>>(Wproj, wp, DMODEL, DMODEL);

    // 1) qkv(bf16) = x @ W_qkv + b_qkv   (plain fp16 MFMA, 2-phase pipelined)
    gemm_f16<1><<<dim3(3 * DMODEL / 128, MROWS / 128), 256, 0, stream>>>(
        xf, wq, bqkv, (void*)qkv, MROWS, 3 * DMODEL, DMODEL);

    // 1b) transpose V section -> vT[b][h][d][s]
    transpose_v<<<dim3(BATCH * NHEAD * (SLEN / 64)), 256, 0, stream>>>(qkv, vT);

    // 2) fused attention: bf16 qkv + vT -> attn (fp16); 64 q-rows/block,
    //    per-wave q/ct split + pair reduce
    attn_mfma<<<dim3(BATCH * NHEAD * (SLEN / 64)), 256, 0, stream>>>(qkv, vT, attnb);

    // 3) out(fp32) = attn @ W_proj + b_proj   (plain fp16 MFMA, 2-phase pipelined)
    gemm_f16<0><<<dim3(DMODEL / 128, MROWS / 128), 256, 0, stream>>>(
        attnb, wp, bproj, (void*)out, MROWS, DMODEL, DMODEL);
}

// Round 10
// 196.302 us; speedup vs baseline: 2.3709x; 1.0503x over previous
//
#include <hip/hip_runtime.h>

// Problem constants
#define BATCH 2
#define SLEN 2048
#define DMODEL 1024
#define NHEAD 16
#define HDIM 64
#define MROWS (BATCH * SLEN)   // 4096

typedef __attribute__((ext_vector_type(8))) short bf16x8;
typedef __attribute__((ext_vector_type(4))) short bf16x4;
typedef __attribute__((ext_vector_type(4))) float f32x4;
typedef __attribute__((ext_vector_type(8))) _Float16 f16x8;
typedef __attribute__((ext_vector_type(4))) _Float16 f16x4;

__device__ inline short f2bf(float x) {
    union { float f; unsigned u; } v; v.f = x;
    unsigned r = (v.u + 0x7FFFu + ((v.u >> 16) & 1u)) >> 16;
    return (short)r;
}
__device__ inline float bf2f(short h) {
    union { unsigned u; float f; } v; v.u = ((unsigned)(unsigned short)h) << 16;
    return v.f;
}
__device__ inline unsigned fbits(float x) {
    union { float f; unsigned u; } v; v.f = x; return v.u;
}
// raw hardware exp2: one v_exp_f32 (args bounded; no denormal fixup needed)
__device__ inline float hw_exp2(float x) {
    float r;
    asm("v_exp_f32 %0, %1" : "=v"(r) : "v"(x));
    return r;
}

// ---------------- fused prep: cast x -> fp16  +  transpose both weight
// matrices to fp16 [N][K]. One launch instead of three (launch-gap probe).
#define NCAST (MROWS * DMODEL / 4 / 256)                    // 4096 blocks
#define NTW1  ((3 * DMODEL / 64) * (DMODEL / 64))           // 48*16 = 768
#define NTW2  ((DMODEL / 64) * (DMODEL / 64))               // 16*16 = 256

__global__ __launch_bounds__(256) void prep(
    const float* __restrict__ x, _Float16* __restrict__ xf,
    const float* __restrict__ Wqkv, _Float16* __restrict__ wq,
    const float* __restrict__ Wproj, _Float16* __restrict__ wp)
{
    __shared__ float T[64][68];
    int bid = blockIdx.x;
    const int tid = threadIdx.x;

    if (bid < NCAST) {            // ---- cast x (uniform per block; no barrier)
        int i = bid * 256 + tid;
        float4 f = ((const float4*)x)[i];
        f16x4 h;
        h[0] = (_Float16)f.x; h[1] = (_Float16)f.y;
        h[2] = (_Float16)f.z; h[3] = (_Float16)f.w;
        ((f16x4*)xf)[i] = h;
        return;
    }
    bid -= NCAST;

    const float* in; _Float16* outT; int N; int n0, k0;
    if (bid < NTW1) {             // ---- transpose W_qkv [1024][3072]
        in = Wqkv; outT = wq; N = 3 * DMODEL;
        n0 = (bid % 48) * 64; k0 = (bid / 48) * 64;
    } else {                      // ---- transpose W_proj [1024][1024]
        bid -= NTW1;
        in = Wproj; outT = wp; N = DMODEL;
        n0 = (bid % 16) * 64; k0 = (bid / 16) * 64;
    }
    const int K = DMODEL;

#pragma unroll
    for (int i = 0; i < 4; i++) {
        int idx = tid + i * 256;
        int r = idx >> 4, c4 = idx & 15;
        *(float4*)&T[r][c4 * 4] = *(const float4*)&in[(size_t)(k0 + r) * N + n0 + c4 * 4];
    }
    __syncthreads();
#pragma unroll
    for (int i = 0; i < 4; i++) {
        int idx = tid + i * 256;
        int n = idx >> 4, kg = idx & 15;
        f16x4 h;
#pragma unroll
        for (int j = 0; j < 4; j++)
            h[j] = (_Float16)T[kg * 4 + j][n];
        *(f16x4*)&outT[(size_t)(n0 + n) * K + k0 + kg * 4] = h;
    }
}

// ---------------- transpose V section of qkv -> vT[b][h][d][s]  (bf16)
__global__ __launch_bounds__(256) void transpose_v(
    const short* __restrict__ qkv, short* __restrict__ vT)
{
    __shared__ short T[64 * 68];   // [s][d], stride 68 shorts
    const int tid = threadIdx.x;
    const int bid = blockIdx.x;
    const int st = bid & 31, h = (bid >> 5) & 15, b = bid >> 9;
    const int s0 = st * 64;
    const short* src = qkv + (size_t)b * SLEN * (3 * DMODEL) + 2 * DMODEL + h * HDIM;

    const int srow = tid >> 3, sc8 = tid & 7;
#pragma unroll
    for (int it = 0; it < 2; it++) {
        int s = srow + it * 32;
        *(bf16x8*)&T[s * 68 + sc8 * 8] =
            *(const bf16x8*)&src[(size_t)(s0 + s) * (3 * DMODEL) + sc8 * 8];
    }
    __syncthreads();

    const int d = tid >> 2, sq = tid & 3;
    short* dst = vT + ((size_t)(b * NHEAD + h) * HDIM + d) * SLEN + s0 + sq * 16;
    bf16x8 o0, o1;
#pragma unroll
    for (int j = 0; j < 8; j++) {
        o0[j] = T[(sq * 16 + j) * 68 + d];
        o1[j] = T[(sq * 16 + 8 + j) * 68 + d];
    }
    *(bf16x8*)&dst[0] = o0;
    *(bf16x8*)&dst[8] = o1;
}

// ---------------- plain fp16 MFMA GEMM: C = A[M,K] · B[K,N] + bias
// B given TRANSPOSED [N][K] fp16. 128x128 tiles, BK=64 (v17):
// two 32-K sub-steps per barrier pair -> barrier count halves vs v14,
// 32 MFMA per phase (was 16) — attacks the 2-barrier drain stall.
// 2-phase register prefetch kept (measured ~17 µs win in v14).
#define GSTR2 72   // LDS row stride (f16): 144 B; read bank-starts {0,4..28} = free 2-way

template<int OUT_BF16>
__global__ __launch_bounds__(256) void gemm_f16(
    const _Float16* __restrict__ A, const _Float16* __restrict__ Bw,
    const float* __restrict__ bias, void* __restrict__ Cout,
    int M, int N, int K)
{
    __shared__ _Float16 As[128 * GSTR2], Bs[128 * GSTR2];

    const int tid  = threadIdx.x;
    const int wave = tid >> 6, lane = tid & 63;
    const int quad = lane >> 4, lr = lane & 15;
    const int wm = (wave >> 1) * 64, wn = (wave & 1) * 64;
    const int row0 = blockIdx.y * 128, col0 = blockIdx.x * 128;

    f32x4 acc[4][4];
#pragma unroll
    for (int i = 0; i < 4; i++)
#pragma unroll
        for (int j = 0; j < 4; j++) acc[i][j] = (f32x4){0.f, 0.f, 0.f, 0.f};

    const int sr = tid >> 2, sc = tid & 3;

    // staging pointers: rows sr / sr+64, K-chunks sc*8 and sc*8+32
    const _Float16* ap0 = A  + (size_t)(row0 + sr) * K + sc * 8;
    const _Float16* ap1 = ap0 + (size_t)64 * K;
    const _Float16* bp0 = Bw + (size_t)(col0 + sr) * K + sc * 8;
    const _Float16* bp1 = bp0 + (size_t)64 * K;

    f16x8 apre[4], bpre[4];
    apre[0] = *(const f16x8*)ap0;        apre[1] = *(const f16x8*)(ap0 + 32);
    apre[2] = *(const f16x8*)ap1;        apre[3] = *(const f16x8*)(ap1 + 32);
    bpre[0] = *(const f16x8*)bp0;        bpre[1] = *(const f16x8*)(bp0 + 32);
    bpre[2] = *(const f16x8*)bp1;        bpre[3] = *(const f16x8*)(bp1 + 32);
    ap0 += 64; ap1 += 64; bp0 += 64; bp1 += 64;

    const int ls = sr * GSTR2 + sc * 8;

    for (int k0 = 0; k0 < K; k0 += 64) {
        // write prefetched 128x64 tiles to LDS (prev reads done: trailing barrier)
        *(f16x8*)&As[ls]                    = apre[0];
        *(f16x8*)&As[ls + 32]               = apre[1];
        *(f16x8*)&As[ls + 64 * GSTR2]       = apre[2];
        *(f16x8*)&As[ls + 64 * GSTR2 + 32]  = apre[3];
        *(f16x8*)&Bs[ls]                    = bpre[0];
        *(f16x8*)&Bs[ls + 32]               = bpre[1];
        *(f16x8*)&Bs[ls + 64 * GSTR2]       = bpre[2];
        *(f16x8*)&Bs[ls + 64 * GSTR2 + 32]  = bpre[3];

        // issue global loads for tile k0+64 (hidden under this tile's compute)
        if (k0 + 64 < K) {
            apre[0] = *(const f16x8*)ap0;        apre[1] = *(const f16x8*)(ap0 + 32);
            apre[2] = *(const f16x8*)ap1;        apre[3] = *(const f16x8*)(ap1 + 32);
            bpre[0] = *(const f16x8*)bp0;        bpre[1] = *(const f16x8*)(bp0 + 32);
            bpre[2] = *(const f16x8*)bp1;        bpre[3] = *(const f16x8*)(bp1 + 32);
            ap0 += 64; ap1 += 64; bp0 += 64; bp1 += 64;
        }

        __syncthreads();

#pragma unroll
        for (int kk = 0; kk < 2; kk++) {
            f16x8 af[4];
#pragma unroll
            for (int mt = 0; mt < 4; mt++)
                af[mt] = *(const f16x8*)&As[(wm + mt * 16 + lr) * GSTR2 + kk * 32 + quad * 8];
#pragma unroll
            for (int nt = 0; nt < 4; nt++) {
                f16x8 b = *(const f16x8*)&Bs[(wn + nt * 16 + lr) * GSTR2 + kk * 32 + quad * 8];
#pragma unroll
                for (int mt = 0; mt < 4; mt++)
                    acc[mt][nt] = __builtin_amdgcn_mfma_f32_16x16x32_f16(af[mt], b, acc[mt][nt], 0, 0, 0);
            }
        }

        __syncthreads();   // reads done; next iter may overwrite LDS
    }

    // epilogue: D[m = quad*4 + r][n = lr]
#pragma unroll
    for (int mt = 0; mt < 4; mt++) {
#pragma unroll
        for (int nt = 0; nt < 4; nt++) {
            int col = col0 + wn + nt * 16 + lr;
            float bv = bias[col];
#pragma unroll
            for (int r = 0; r < 4; r++) {
                int row = row0 + wm + mt * 16 + quad * 4 + r;
                float v = acc[mt][nt][r] + bv;
                if (OUT_BF16)
                    ((short*)Cout)[(size_t)row * N + col] = f2bf(v);
                else
                    ((float*)Cout)[(size_t)row * N + col] = v;
            }
        }
    }
}

// ---------------- fused attention v16 (verified, 65.5 µs): q/ct split per
// wave + pair-reduce epilogue. NOTE: plain __launch_bounds__(256) — the
// (256,4) min-occupancy cap produced silently-wrong spill codegen twice
// (v10, v15); do not reintroduce.
#define ASTR 72   // LDS row stride (shorts): 144 B, 16B-aligned rows
#define NT   (SLEN / 64)
#define RSTR 20   // epilogue float row stride (80 B, 16B-aligned)
#define QK_SCALE_LOG2E 0.1803368801111244f   // 0.125 * log2(e)

__global__ __launch_bounds__(256) void attn_mfma(
    const short* __restrict__ qkv, const short* __restrict__ vT,
    _Float16* __restrict__ attn)
{
    // single pool: main loop = Ks[2][64*ASTR] + Vt[2][64*ASTR] shorts (36864 B);
    // epilogue reuses it as float [4][64][RSTR] (20480 B).
    __shared__ __align__(16) char smem[2 * 64 * ASTR * 2 * 2];
    short* KsBuf = (short*)smem;
    short* VtBuf = KsBuf + 2 * 64 * ASTR;

    const int tid  = threadIdx.x;
    const int lane = tid & 63;
    const int wave = tid >> 6;
    const int quad = lane >> 4;
    const int lr   = lane & 15;
    const int qhalf  = wave >> 1;        // which 32-q half this wave owns
    const int cthalf = wave & 1;         // which ct pair this wave owns

    const int bid = blockIdx.x;
    const int qt = bid & 31;             // 32 q-tiles of 64
    const int h  = (bid >> 5) & 15;
    const int b  = bid >> 9;
    const int q0 = qt * 64;

    const short* qbase = qkv + (size_t)b * SLEN * (3 * DMODEL) + h * HDIM;
    const short* kbase = qbase + DMODEL;
    const short* vtbase = vT + (size_t)(b * NHEAD + h) * HDIM * SLEN;

    // 2 q-subtiles as 16x16x32 B-frags, pre-scaled:
    // qf[qs][ds2][j] = Q[q0 + qhalf*32 + qs*16 + lr][ds2*32 + quad*8 + j]
    bf16x8 qf[2][2];
#pragma unroll
    for (int qs = 0; qs < 2; qs++)
#pragma unroll
        for (int ds2 = 0; ds2 < 2; ds2++) {
            bf16x8 q = *(const bf16x8*)&qbase[(size_t)(q0 + qhalf * 32 + qs * 16 + lr) * (3 * DMODEL) + ds2 * 32 + quad * 8];
#pragma unroll
            for (int j = 0; j < 8; j++)
                q[j] = f2bf(bf2f(q[j]) * QK_SCALE_LOG2E);
            qf[qs][ds2] = q;
        }

    // ones A-fragment for the row-sum MFMA (x16 shape)
    bf16x4 ones;
#pragma unroll
    for (int j = 0; j < 4; j++) ones[j] = (short)0x3F80;

    f32x4 oacc[2][4];   // [qs][dt]: O^T partial over this wave's keys
#pragma unroll
    for (int qs = 0; qs < 2; qs++)
#pragma unroll
        for (int t = 0; t < 4; t++) oacc[qs][t] = (f32x4){0.f, 0.f, 0.f, 0.f};
    f32x4 sacc[2] = {{0.f, 0.f, 0.f, 0.f}, {0.f, 0.f, 0.f, 0.f}};

    const int srow = tid >> 3, sc8 = tid & 7;

    // pointer-bumped staging addresses (all 4 waves stage the full tile)
    const short* kp0 = kbase + (size_t)srow * (3 * DMODEL) + sc8 * 8;
    const short* kp1 = kp0 + 32 * (3 * DMODEL);
    const short* vp0 = vtbase + (size_t)srow * SLEN + sc8 * 8;
    const short* vp1 = vp0 + 32 * SLEN;

    bf16x8 kpre[2], vpre[2];
    kpre[0] = *(const bf16x8*)kp0; kpre[1] = *(const bf16x8*)kp1;
    vpre[0] = *(const bf16x8*)vp0; vpre[1] = *(const bf16x8*)vp1;
    kp0 += 64 * (3 * DMODEL); kp1 += 64 * (3 * DMODEL);
    vp0 += 64; vp1 += 64;

    for (int kt = 0; kt < NT; kt++) {
        const int cur = kt & 1;
        short* ks = KsBuf + cur * 64 * ASTR;
        short* vt = VtBuf + cur * 64 * ASTR;

        // write tile kt (in regs) to LDS buffer `cur`
        *(bf16x8*)&ks[srow * ASTR + sc8 * 8] = kpre[0];
        *(bf16x8*)&ks[(srow + 32) * ASTR + sc8 * 8] = kpre[1];
        *(bf16x8*)&vt[srow * ASTR + sc8 * 8] = vpre[0];
        *(bf16x8*)&vt[(srow + 32) * ASTR + sc8 * 8] = vpre[1];

        // issue global loads for tile kt+1
        if (kt + 1 < NT) {
            kpre[0] = *(const bf16x8*)kp0; kpre[1] = *(const bf16x8*)kp1;
            vpre[0] = *(const bf16x8*)vp0; vpre[1] = *(const bf16x8*)vp1;
            kp0 += 64 * (3 * DMODEL); kp1 += 64 * (3 * DMODEL);
            vp0 += 64; vp1 += 64;
        }

        __syncthreads();   // buffer `cur` complete; reads of 1-cur done pre-barrier

        // this wave's 2 key sub-tiles x 2 q-subtiles (4 chains/kt)
#pragma unroll
        for (int ct2 = 0; ct2 < 2; ct2++) {
            const int ct = cthalf * 2 + ct2;
            bf16x8 kf0 = *(const bf16x8*)&ks[(ct * 16 + lr) * ASTR + quad * 8];
            bf16x8 kf1 = *(const bf16x8*)&ks[(ct * 16 + lr) * ASTR + 32 + quad * 8];
            bf16x4 vf0 = *(const bf16x4*)&vt[(0 * 16 + lr) * ASTR + ct * 16 + quad * 4];
            bf16x4 vf1 = *(const bf16x4*)&vt[(1 * 16 + lr) * ASTR + ct * 16 + quad * 4];
            bf16x4 vf2 = *(const bf16x4*)&vt[(2 * 16 + lr) * ASTR + ct * 16 + quad * 4];
            bf16x4 vf3 = *(const bf16x4*)&vt[(3 * 16 + lr) * ASTR + ct * 16 + quad * 4];

#pragma unroll
            for (int qs = 0; qs < 2; qs++) {
                f32x4 st = {0.f, 0.f, 0.f, 0.f};
                st = __builtin_amdgcn_mfma_f32_16x16x32_bf16(kf0, qf[qs][0], st, 0, 0, 0);
                st = __builtin_amdgcn_mfma_f32_16x16x32_bf16(kf1, qf[qs][1], st, 0, 0, 0);

                float p0[4];
#pragma unroll
                for (int r = 0; r < 4; r++) p0[r] = hw_exp2(st[r]);
                union { uint2 u; bf16x4 v; } pk0;
                pk0.u.x = __builtin_amdgcn_perm(fbits(p0[1]), fbits(p0[0]), 0x07060302u);
                pk0.u.y = __builtin_amdgcn_perm(fbits(p0[3]), fbits(p0[2]), 0x07060302u);
                bf16x4 pf0 = pk0.v;

                sacc[qs] = __builtin_amdgcn_mfma_f32_16x16x16bf16_1k(ones, pf0, sacc[qs], 0, 0, 0);
                oacc[qs][0] = __builtin_amdgcn_mfma_f32_16x16x16bf16_1k(vf0, pf0, oacc[qs][0], 0, 0, 0);
                oacc[qs][1] = __builtin_amdgcn_mfma_f32_16x16x16bf16_1k(vf1, pf0, oacc[qs][1], 0, 0, 0);
                oacc[qs][2] = __builtin_amdgcn_mfma_f32_16x16x16bf16_1k(vf2, pf0, oacc[qs][2], 0, 0, 0);
                oacc[qs][3] = __builtin_amdgcn_mfma_f32_16x16x16bf16_1k(vf3, pf0, oacc[qs][3], 0, 0, 0);
            }
        }
    }

    // ---- epilogue: pair (wave, wave^1) shares qhalf; reduce over cthalf.
    __syncthreads();                       // all main-loop LDS reads done
    float* Lf = (float*)smem;              // [4 waves][64 lanes][RSTR]
    float* myrow = Lf + (wave * 64 + lane) * RSTR;

    // round 0 stage (cthalf==1)
    if (cthalf == 1) {
        *(f32x4*)&myrow[0]  = oacc[0][0];
        *(f32x4*)&myrow[4]  = oacc[0][1];
        *(f32x4*)&myrow[8]  = oacc[0][2];
        *(f32x4*)&myrow[12] = oacc[0][3];
        myrow[16] = sacc[0][0];
    }
    __syncthreads();
    if (cthalf == 0) {
        // finalize qs=0
        const float* pr = Lf + ((wave ^ 1) * 64 + lane) * RSTR;
        f32x4 o0 = oacc[0][0] + *(const f32x4*)&pr[0];
        f32x4 o1 = oacc[0][1] + *(const f32x4*)&pr[4];
        f32x4 o2 = oacc[0][2] + *(const f32x4*)&pr[8];
        f32x4 o3 = oacc[0][3] + *(const f32x4*)&pr[12];
        const float inv = 1.0f / (sacc[0][0] + pr[16]);
        const int row = b * SLEN + q0 + qhalf * 32 + lr;
        f16x4 h4;
#pragma unroll
        for (int r = 0; r < 4; r++) h4[r] = (_Float16)(o0[r] * inv);
        *(f16x4*)&attn[(size_t)row * DMODEL + h * HDIM + 0 * 16 + quad * 4] = h4;
#pragma unroll
        for (int r = 0; r < 4; r++) h4[r] = (_Float16)(o1[r] * inv);
        *(f16x4*)&attn[(size_t)row * DMODEL + h * HDIM + 1 * 16 + quad * 4] = h4;
#pragma unroll
        for (int r = 0; r < 4; r++) h4[r] = (_Float16)(o2[r] * inv);
        *(f16x4*)&attn[(size_t)row * DMODEL + h * HDIM + 2 * 16 + quad * 4] = h4;
#pragma unroll
        for (int r = 0; r < 4; r++) h4[r] = (_Float16)(o3[r] * inv);
        *(f16x4*)&attn[(size_t)row * DMODEL + h * HDIM + 3 * 16 + quad * 4] = h4;
        // round 1 stage (cthalf==0)
        *(f32x4*)&myrow[0]  = oacc[1][0];
        *(f32x4*)&myrow[4]  = oacc[1][1];
        *(f32x4*)&myrow[8]  = oacc[1][2];
        *(f32x4*)&myrow[12] = oacc[1][3];
        myrow[16] = sacc[1][0];
    }
    __syncthreads();
    if (cthalf == 1) {
        // finalize qs=1
        const float* pr = Lf + ((wave ^ 1) * 64 + lane) * RSTR;
        f32x4 o0 = oacc[1][0] + *(const f32x4*)&pr[0];
        f32x4 o1 = oacc[1][1] + *(const f32x4*)&pr[4];
        f32x4 o2 = oacc[1][2] + *(const f32x4*)&pr[8];
        f32x4 o3 = oacc[1][3] + *(const f32x4*)&pr[12];
        const float inv = 1.0f / (sacc[1][0] + pr[16]);
        const int row = b * SLEN + q0 + qhalf * 32 + 16 + lr;
        f16x4 h4;
#pragma unroll
        for (int r = 0; r < 4; r++) h4[r] = (_Float16)(o0[r] * inv);
        *(f16x4*)&attn[(size_t)row * DMODEL + h * HDIM + 0 * 16 + quad * 4] = h4;
#pragma unroll
        for (int r = 0; r < 4; r++) h4[r] = (_Float16)(o1[r] * inv);
        *(f16x4*)&attn[(size_t)row * DMODEL + h * HDIM + 1 * 16 + quad * 4] = h4;
#pragma unroll
        for (int r = 0; r < 4; r++) h4[r] = (_Float16)(o2[r] * inv);
        *(f16x4*)&attn[(size_t)row * DMODEL + h * HDIM + 2 * 16 + quad * 4] = h4;
#pragma unroll
        for (int r = 0; r < 4; r++) h4[r] = (_Float16)(o3[r] * inv);
        *(f16x4*)&attn[(size_t)row * DMODEL + h * HDIM + 3 * 16 + quad * 4] = h4;
    }
}

extern "C" void kernel_launch(void* const* d_in, const int* in_sizes, int n_in,
                              void* d_out, int out_size, void* d_ws, size_t ws_size,
                              hipStream_t stream) {
    (void)in_sizes; (void)n_in; (void)out_size; (void)ws_size;
    const float* x     = (const float*)d_in[0];
    const float* Wqkv  = (const float*)d_in[1];
    const float* bqkv  = (const float*)d_in[2];
    const float* Wproj = (const float*)d_in[3];
    const float* bproj = (const float*)d_in[4];
    float* out = (float*)d_out;

    // workspace layout (2-byte units), peak ~58.6 MB
    short* qkv = (short*)d_ws;                               // 4096*3072 bf16
    _Float16* xf = (_Float16*)(qkv + (size_t)MROWS * 3 * DMODEL);  // 4096*1024 f16
    _Float16* wq = xf + (size_t)MROWS * DMODEL;              // 3072*1024 f16 (W_qkv^T)
    _Float16* wp = wq + (size_t)3 * DMODEL * DMODEL;         // 1024*1024 f16 (W_proj^T)
    short* vT = (short*)(wp + (size_t)DMODEL * DMODEL);      // 4096*1024 bf16
    _Float16* attnb = (_Float16*)(vT + (size_t)MROWS * DMODEL); // 4096*1024 f16

    // 0) fused prep: cast x; transpose both weights (one launch)
    prep<<<dim3(NCAST + NTW1 + NTW2), 256, 0, stream>>>(x, xf, Wqkv, wq, Wproj, wp);

    // 1) qkv(bf16) = x @ W_qkv + b_qkv   (fp16 MFMA, BK=64, 2-phase)
    gemm_f16<1><<<dim3(3 * DMODEL / 128, MROWS / 128), 256, 0, stream>>>(
        xf, wq, bqkv, (void*)qkv, MROWS, 3 * DMODEL, DMODEL);

    // 1b) transpose V section -> vT[b][h][d][s]
    transpose_v<<<dim3(BATCH * NHEAD * (SLEN / 64)), 256, 0, stream>>>(qkv, vT);

    // 2) fused attention: bf16 qkv + vT -> attn (fp16); 64 q-rows/block,
    //    per-wave q/ct split + pair reduce
    attn_mfma<<<dim3(BATCH * NHEAD * (SLEN / 64)), 256, 0, stream>>>(qkv, vT, attnb);

    // 3) out(fp32) = attn @ W_proj + b_proj   (fp16 MFMA, BK=64, 2-phase)
    gemm_f16<0><<<dim3(DMODEL / 128, MROWS / 128), 256, 0, stream>>>(
        attnb, wp, bproj, (void*)out, MROWS, DMODEL, DMODEL);
}